// Round 3
// baseline (424.700 us; speedup 1.0000x reference)
//
#include <hip/hip_runtime.h>
#include <hip/hip_bf16.h>

#define NNODES 50000
#define NEDGES 150000
#define DFEAT  512
#define HID    512
#define NCLS   47

typedef __hip_bfloat16 bf16;
typedef __attribute__((ext_vector_type(8))) short short8;
typedef __attribute__((ext_vector_type(4))) float float4v;

typedef const __attribute__((address_space(1))) unsigned int* gas_t;
typedef __attribute__((address_space(3))) unsigned int* las_t;
__device__ __forceinline__ void load_lds16(const void* g, void* l) {
    __builtin_amdgcn_global_load_lds((gas_t)g, (las_t)l, 16, 0, 0);
}

__device__ __forceinline__ float bfbits_lo(unsigned int w) {
    return __uint_as_float((w & 0xFFFFu) << 16);
}
__device__ __forceinline__ float bfbits_hi(unsigned int w) {
    return __uint_as_float(w & 0xFFFF0000u);
}

// ---------------- dtype detection (1 block, 64 threads) ----------------
__global__ void k_detect(const void* x, const void* ei, int* flags) {
    __shared__ int scnt[64], sor[64];
    int t = threadIdx.x;
    const unsigned short* xs = (const unsigned short*)x;
    int c = 0;
    for (int i = t; i < 256; i += 64) {
        unsigned int e = (xs[2 * i] >> 7) & 0xFF;
        c += (e >= 117 && e <= 130) ? 1 : 0;
    }
    const int* w = (const int*)ei;
    int o = 0;
    for (int i = 2 * t + 1; i < 512; i += 128) o |= w[i];
    scnt[t] = c; sor[t] = o;
    __syncthreads();
    if (t == 0) {
        int C = 0, O = 0;
        for (int i = 0; i < 64; i++) { C += scnt[i]; O |= sor[i]; }
        flags[0] = (C > 128) ? 1 : 0;
        flags[1] = (O == 0) ? 1 : 0;
    }
}

__device__ __forceinline__ int eidx(const void* ei, int half, int e, int is64) {
    if (is64) return (int)((const long long*)ei)[(size_t)half * NEDGES + e];
    return ((const int*)ei)[half * NEDGES + e];
}

// ---------------- utility ----------------
__global__ void k_zero32(unsigned int* p, size_t n) {
    size_t i = (size_t)blockIdx.x * blockDim.x + threadIdx.x;
    if (i < n) p[i] = 0u;
}

__global__ void k_cvt(const void* src, float* dst, int n, const int* flags) {
    int i = blockIdx.x * blockDim.x + threadIdx.x;
    if (i >= n) return;
    dst[i] = flags[0] ? __bfloat162float(((const bf16*)src)[i]) : ((const float*)src)[i];
}

// W1 [K=512][N=512] -> W1T bf16 [N][K]
__global__ void k_cvt_w1t(const void* W1, bf16* W1T, const int* flags) {
    int i = blockIdx.x * blockDim.x + threadIdx.x;
    if (i >= DFEAT * HID) return;
    int k = i / HID, n = i % HID;
    float v = flags[0] ? __bfloat162float(((const bf16*)W1)[i]) : ((const float*)W1)[i];
    W1T[(size_t)n * DFEAT + k] = __float2bfloat16(v);
}

// W2 [K=512][N=47] -> W2T bf16 [64][512] zero-padded
__global__ void k_cvt_w2t(const void* W2, bf16* W2T, const int* flags) {
    int i = blockIdx.x * blockDim.x + threadIdx.x;
    if (i >= 64 * HID) return;
    int n = i / HID, k = i % HID;
    float v = 0.0f;
    if (n < NCLS) {
        size_t idx = (size_t)k * NCLS + n;
        v = flags[0] ? __bfloat162float(((const bf16*)W2)[idx]) : ((const float*)W2)[idx];
    }
    W2T[(size_t)n * HID + k] = __float2bfloat16(v);
}

// ---------------- graph structure ----------------
__global__ void k_count(const void* ei, int* cnt, const int* flags) {
    int e = blockIdx.x * blockDim.x + threadIdx.x;
    if (e >= NEDGES) return;
    atomicAdd(&cnt[eidx(ei, 1, e, flags[1])], 1);
}

__global__ void k_dinv(const int* cnt, float* dinv) {
    int i = blockIdx.x * blockDim.x + threadIdx.x;
    if (i < NNODES) dinv[i] = rsqrtf(1.0f + (float)cnt[i]);
}

__global__ __launch_bounds__(256) void k_scan_part(const int* cnt, int* part) {
    __shared__ int s[256];
    int i = blockIdx.x * 256 + threadIdx.x;
    s[threadIdx.x] = (i < NNODES) ? cnt[i] : 0;
    __syncthreads();
    for (int off = 128; off > 0; off >>= 1) {
        if (threadIdx.x < off) s[threadIdx.x] += s[threadIdx.x + off];
        __syncthreads();
    }
    if (threadIdx.x == 0) part[blockIdx.x] = s[0];
}

__global__ __launch_bounds__(256) void k_scan_off(int* part, int n) {
    __shared__ int s[256];
    int v = (threadIdx.x < n) ? part[threadIdx.x] : 0;
    s[threadIdx.x] = v;
    __syncthreads();
    for (int off = 1; off < 256; off <<= 1) {
        int t = (threadIdx.x >= off) ? s[threadIdx.x - off] : 0;
        __syncthreads();
        s[threadIdx.x] += t;
        __syncthreads();
    }
    if (threadIdx.x < n) part[threadIdx.x] = s[threadIdx.x] - v;
}

__global__ __launch_bounds__(256) void k_scan_fin(const int* cnt, const int* part,
                                                  int* rowptr, int* cursor) {
    __shared__ int s[256];
    int i = blockIdx.x * 256 + threadIdx.x;
    int v = (i < NNODES) ? cnt[i] : 0;
    s[threadIdx.x] = v;
    __syncthreads();
    for (int off = 1; off < 256; off <<= 1) {
        int t = (threadIdx.x >= off) ? s[threadIdx.x - off] : 0;
        __syncthreads();
        s[threadIdx.x] += t;
        __syncthreads();
    }
    int incl = s[threadIdx.x] + part[blockIdx.x];
    if (i < NNODES) {
        rowptr[i + 1] = incl;
        cursor[i] = incl - v;
    }
    if (i == 0) rowptr[0] = 0;
}

__global__ void k_fill(const void* ei, int* cursor, int* csr_src, const int* flags) {
    int e = blockIdx.x * blockDim.x + threadIdx.x;
    if (e >= NEDGES) return;
    int is64 = flags[1];
    int v = eidx(ei, 1, e, is64);
    int u = eidx(ei, 0, e, is64);
    int pos = atomicAdd(&cursor[v], 1);
    csr_src[pos] = u;
}

// ---- direct-from-global MFMA fragment loads (no LDS, no barriers) ----
// A-fragment: lane l -> 16B of row (base + (l&15)) at k + (l>>4)*8.
__device__ __forceinline__ short8 afrag_bf(const bf16* X, int row, int k) {
    return *(const short8*)(X + (size_t)row * DFEAT + k);
}
__device__ __forceinline__ short8 afrag_f32(const float* X, int row, int k) {
    const float* p = X + (size_t)row * DFEAT + k;
    float4v f0 = *(const float4v*)p;
    float4v f1 = *(const float4v*)(p + 4);
    short8 r;
    bf16* rb = (bf16*)&r;
    rb[0] = __float2bfloat16(f0[0]); rb[1] = __float2bfloat16(f0[1]);
    rb[2] = __float2bfloat16(f0[2]); rb[3] = __float2bfloat16(f0[3]);
    rb[4] = __float2bfloat16(f1[0]); rb[5] = __float2bfloat16(f1[1]);
    rb[6] = __float2bfloat16(f1[2]); rb[7] = __float2bfloat16(f1[3]);
    return r;
}

// ---------------- GEMM1 v6: register-direct, zero LDS, zero barriers ----------
// Rationale: A (x rows) has NO cross-wave reuse -> LDS staging only added a
// per-K-step barrier rendezvous (the measured latency wall: MfmaUtil 8%,
// all pipes idle). B (W1T, 512 KB) is permanently L2-resident and its per-
// K-step slice is L1-resident; all 4 waves of a block read the SAME B
// fragments (L1 broadcast). So load both operands straight into VGPRs in
// fragment layout (16 rows x 64B contiguous per dwordx4) and let the
// compiler pipeline the 10 independent loads per K-step across iterations.
// XCD remap keeps the 4 col-tiles of a row-tile on one XCD -> x fetched
// from HBM once (L2 reuse), as in v3.
__global__ __launch_bounds__(256, 3) void k_gemm1_v6(
    const void* __restrict__ X, const bf16* __restrict__ W1T,
    bf16* __restrict__ h1c, int c0, int C, const int* __restrict__ flags,
    int col_tiles, int rows_per_xcd, int n_row_tiles) {
    const int b = blockIdx.x;
    const int xcd = b & 7;
    const int s = b >> 3;
    const int col_t = s % col_tiles;
    const int lr = s / col_tiles;
    const int row_t = xcd * rows_per_xcd + lr;
    if (row_t >= n_row_tiles) return;

    const int tid = threadIdx.x;
    const int wave = tid >> 6, lane = tid & 63;
    const int row0 = row_t * 128;
    const int gc0 = c0 + col_t * 128;
    const int isb = flags[0];

    const int rb = wave * 32;
    const int frow = lane & 15;
    const int fko = (lane >> 4) * 8;   // k sub-offset within fragment

    // per-lane A rows (clamped), B cols
    int ar[2];
#pragma unroll
    for (int i = 0; i < 2; i++) {
        int gr = row0 + rb + i * 16 + frow;
        ar[i] = (gr >= NNODES) ? NNODES - 1 : gr;
    }

    float4v acc[2][8];
#pragma unroll
    for (int i = 0; i < 2; i++)
#pragma unroll
        for (int j = 0; j < 8; j++) acc[i][j] = (float4v){0.f, 0.f, 0.f, 0.f};

    const bf16* xb = (const bf16*)X;
    const float* xf = (const float*)X;

    if (isb) {
#pragma unroll 4
        for (int k0 = 0; k0 < DFEAT; k0 += 32) {
            const int kk = k0 + fko;
            short8 a[2], b8[8];
#pragma unroll
            for (int i = 0; i < 2; i++) a[i] = afrag_bf(xb, ar[i], kk);
#pragma unroll
            for (int j = 0; j < 8; j++)
                b8[j] = *(const short8*)(W1T + (size_t)(gc0 + j * 16 + frow) * DFEAT + kk);
#pragma unroll
            for (int i = 0; i < 2; i++)
#pragma unroll
                for (int j = 0; j < 8; j++)
                    acc[i][j] = __builtin_amdgcn_mfma_f32_16x16x32_bf16(a[i], b8[j], acc[i][j], 0, 0, 0);
        }
    } else {
#pragma unroll 2
        for (int k0 = 0; k0 < DFEAT; k0 += 32) {
            const int kk = k0 + fko;
            short8 a[2], b8[8];
#pragma unroll
            for (int i = 0; i < 2; i++) a[i] = afrag_f32(xf, ar[i], kk);
#pragma unroll
            for (int j = 0; j < 8; j++)
                b8[j] = *(const short8*)(W1T + (size_t)(gc0 + j * 16 + frow) * DFEAT + kk);
#pragma unroll
            for (int i = 0; i < 2; i++)
#pragma unroll
                for (int j = 0; j < 8; j++)
                    acc[i][j] = __builtin_amdgcn_mfma_f32_16x16x32_bf16(a[i], b8[j], acc[i][j], 0, 0, 0);
        }
    }

    const int ccol = gc0 - c0;
#pragma unroll
    for (int i = 0; i < 2; i++) {
#pragma unroll
        for (int r = 0; r < 4; r++) {
            int grow = row0 + rb + i * 16 + (lane >> 4) * 4 + r;
            if (grow < NNODES) {
#pragma unroll
                for (int j = 0; j < 8; j++)
                    h1c[(size_t)grow * C + ccol + j * 16 + frow] =
                        __float2bfloat16(acc[i][j][r]);
            }
        }
    }
}

// ---------------- legacy GEMM1 (C==64 fallback) ----------------
__global__ __launch_bounds__(256) void k_gemm1_mfma(
    const void* __restrict__ X, const bf16* __restrict__ W1T,
    bf16* __restrict__ h1c, int c0, int C, const int* __restrict__ flags) {
    __shared__ bf16 As[128 * 64];
    __shared__ bf16 Bs[64 * 64];
    const int tid = threadIdx.x;
    const int wave = tid >> 6, lane = tid & 63;
    const int row0 = blockIdx.x * 128;
    const int gc0 = c0 + blockIdx.y * 64;
    const int isb = flags[0];
    float4v acc[2][4];
#pragma unroll
    for (int i = 0; i < 2; i++)
#pragma unroll
        for (int j = 0; j < 4; j++) acc[i][j] = (float4v){0.f, 0.f, 0.f, 0.f};
    const int rbase = wave * 32;
    const int fl_row = lane & 15;
    const int fl_k8 = (lane >> 4) * 8;
    for (int k0 = 0; k0 < DFEAT; k0 += 64) {
        __syncthreads();
        if (isb) {
            const bf16* xb = (const bf16*)X;
#pragma unroll
            for (int i = 0; i < 4; ++i) {
                int r = i * 32 + wave * 8;
                int gr = row0 + r + (lane >> 3);
                if (gr >= NNODES) gr = NNODES - 1;
                load_lds16(xb + (size_t)gr * DFEAT + k0 + (lane & 7) * 8, &As[r * 64]);
            }
        } else {
            const float* xf = (const float*)X;
            for (int i = tid; i < 128 * 64; i += 256) {
                int r = i >> 6, c = i & 63;
                int gr = row0 + r;
                if (gr >= NNODES) gr = NNODES - 1;
                As[i] = __float2bfloat16(xf[(size_t)gr * DFEAT + k0 + c]);
            }
        }
#pragma unroll
        for (int i = 0; i < 2; ++i) {
            int r = i * 32 + wave * 8;
            int gn = gc0 + r + (lane >> 3);
            load_lds16(W1T + (size_t)gn * DFEAT + k0 + (lane & 7) * 8, &Bs[r * 64]);
        }
        __syncthreads();
#pragma unroll
        for (int ki = 0; ki < 64; ki += 32) {
            short8 a[2], b[4];
#pragma unroll
            for (int i = 0; i < 2; i++)
                a[i] = *(const short8*)&As[(rbase + i * 16 + fl_row) * 64 + ki + fl_k8];
#pragma unroll
            for (int j = 0; j < 4; j++)
                b[j] = *(const short8*)&Bs[(j * 16 + fl_row) * 64 + ki + fl_k8];
#pragma unroll
            for (int i = 0; i < 2; i++)
#pragma unroll
                for (int j = 0; j < 4; j++)
                    acc[i][j] = __builtin_amdgcn_mfma_f32_16x16x32_bf16(a[i], b[j], acc[i][j], 0, 0, 0);
        }
    }
    const int ccol = blockIdx.y * 64;
#pragma unroll
    for (int i = 0; i < 2; i++) {
#pragma unroll
        for (int r = 0; r < 4; r++) {
            int grow = row0 + rbase + i * 16 + (lane >> 4) * 4 + r;
            if (grow < NNODES) {
#pragma unroll
                for (int j = 0; j < 4; j++)
                    h1c[(size_t)grow * C + ccol + j * 16 + (lane & 15)] =
                        __float2bfloat16(acc[i][j][r]);
            }
        }
    }
}

// ---------------- layer1 aggregation, C=512: one wave per node, uint4 loads ----
__global__ __launch_bounds__(256) void k_agg1_512(const bf16* __restrict__ h1c,
                                                  const int* __restrict__ rowptr,
                                                  const int* __restrict__ csr_src,
                                                  const float* __restrict__ dinv,
                                                  const float* __restrict__ b1c,
                                                  bf16* __restrict__ a1c) {
    int v = blockIdx.x * 4 + (threadIdx.x >> 6);
    int lane = threadIdx.x & 63;
    if (v >= NNODES) return;
    int d8 = lane * 8;
    float dv = dinv[v];
    float s2 = dv * dv;
    uint4 w = *(const uint4*)(h1c + (size_t)v * 512 + d8);
    float a0 = s2 * bfbits_lo(w.x), a1 = s2 * bfbits_hi(w.x);
    float a2 = s2 * bfbits_lo(w.y), a3 = s2 * bfbits_hi(w.y);
    float a4 = s2 * bfbits_lo(w.z), a5 = s2 * bfbits_hi(w.z);
    float a6 = s2 * bfbits_lo(w.w), a7 = s2 * bfbits_hi(w.w);
    int pend = rowptr[v + 1];
    for (int p = rowptr[v]; p < pend; ++p) {
        int u = csr_src[p];
        float nw = dinv[u] * dv;
        uint4 q = *(const uint4*)(h1c + (size_t)u * 512 + d8);
        a0 += nw * bfbits_lo(q.x); a1 += nw * bfbits_hi(q.x);
        a2 += nw * bfbits_lo(q.y); a3 += nw * bfbits_hi(q.y);
        a4 += nw * bfbits_lo(q.z); a5 += nw * bfbits_hi(q.z);
        a6 += nw * bfbits_lo(q.w); a7 += nw * bfbits_hi(q.w);
    }
    const float* bb = b1c + d8;
    a0 += bb[0]; a1 += bb[1]; a2 += bb[2]; a3 += bb[3];
    a4 += bb[4]; a5 += bb[5]; a6 += bb[6]; a7 += bb[7];
    bf16 o[8];
    o[0] = __float2bfloat16(a0 > 0.f ? a0 : 0.f);
    o[1] = __float2bfloat16(a1 > 0.f ? a1 : 0.f);
    o[2] = __float2bfloat16(a2 > 0.f ? a2 : 0.f);
    o[3] = __float2bfloat16(a3 > 0.f ? a3 : 0.f);
    o[4] = __float2bfloat16(a4 > 0.f ? a4 : 0.f);
    o[5] = __float2bfloat16(a5 > 0.f ? a5 : 0.f);
    o[6] = __float2bfloat16(a6 > 0.f ? a6 : 0.f);
    o[7] = __float2bfloat16(a7 > 0.f ? a7 : 0.f);
    *(uint4*)(a1c + (size_t)v * 512 + d8) = *(uint4*)o;
}

// ---------------- layer1 aggregation, generic ----------------
__global__ __launch_bounds__(256) void k_agg1(const bf16* __restrict__ h1c,
                                              const int* __restrict__ rowptr,
                                              const int* __restrict__ csr_src,
                                              const float* __restrict__ dinv,
                                              const float* __restrict__ b1c, int c0, int C,
                                              bf16* __restrict__ a1c) {
    const int tshift = (C == 512) ? 7 : (C == 256) ? 6 : (C == 128) ? 5 : 4;
    long long gt = (long long)blockIdx.x * 256 + threadIdx.x;
    int v = (int)(gt >> tshift);
    int d4 = (int)((gt & ((1 << tshift) - 1)) << 2);
    if (v >= NNODES) return;
    float dv = dinv[v];
    uint2 w = *(const uint2*)(h1c + (size_t)v * C + d4);
    float s2 = dv * dv;
    float a0 = s2 * bfbits_lo(w.x), a1 = s2 * bfbits_hi(w.x);
    float a2 = s2 * bfbits_lo(w.y), a3 = s2 * bfbits_hi(w.y);
    int pend = rowptr[v + 1];
    for (int p = rowptr[v]; p < pend; ++p) {
        int u = csr_src[p];
        float nw = dinv[u] * dv;
        uint2 q = *(const uint2*)(h1c + (size_t)u * C + d4);
        a0 += nw * bfbits_lo(q.x); a1 += nw * bfbits_hi(q.x);
        a2 += nw * bfbits_lo(q.y); a3 += nw * bfbits_hi(q.y);
    }
    const float* bb = b1c + c0 + d4;
    a0 += bb[0]; a1 += bb[1]; a2 += bb[2]; a3 += bb[3];
    bf16 o[4];
    o[0] = __float2bfloat16(a0 > 0.f ? a0 : 0.f);
    o[1] = __float2bfloat16(a1 > 0.f ? a1 : 0.f);
    o[2] = __float2bfloat16(a2 > 0.f ? a2 : 0.f);
    o[3] = __float2bfloat16(a3 > 0.f ? a3 : 0.f);
    *(uint2*)(a1c + (size_t)v * C + d4) = *(uint2*)o;
}

// ---------------- GEMM2 v4: register-direct, zero LDS, zero barriers ----------
// W2T is 64 KB -> L1/L2-resident; A (a1c) streamed once. All 4 waves of a
// block read the same B fragments (L1 broadcast).
__global__ __launch_bounds__(256, 4) void k_gemm2_v4(
    const bf16* __restrict__ A, int C, const bf16* __restrict__ W2T, int kg0,
    float* __restrict__ h2, int accum) {
    const int tid = threadIdx.x;
    const int wave = tid >> 6, lane = tid & 63;
    const int row0 = blockIdx.x * 128;
    const int rb = wave * 32;
    const int frow = lane & 15;
    const int fko = (lane >> 4) * 8;

    int ar[2];
#pragma unroll
    for (int i = 0; i < 2; i++) {
        int gr = row0 + rb + i * 16 + frow;
        ar[i] = (gr >= NNODES) ? NNODES - 1 : gr;
    }

    float4v acc[2][4];
#pragma unroll
    for (int i = 0; i < 2; i++)
#pragma unroll
        for (int j = 0; j < 4; j++) acc[i][j] = (float4v){0.f, 0.f, 0.f, 0.f};

#pragma unroll 4
    for (int k0 = 0; k0 < C; k0 += 32) {
        const int kk = k0 + fko;
        short8 a[2], b4[4];
#pragma unroll
        for (int i = 0; i < 2; i++)
            a[i] = *(const short8*)(A + (size_t)ar[i] * C + kk);
#pragma unroll
        for (int j = 0; j < 4; j++)
            b4[j] = *(const short8*)(W2T + (size_t)(j * 16 + frow) * HID + kg0 + kk);
#pragma unroll
        for (int i = 0; i < 2; i++)
#pragma unroll
            for (int j = 0; j < 4; j++)
                acc[i][j] = __builtin_amdgcn_mfma_f32_16x16x32_bf16(a[i], b4[j], acc[i][j], 0, 0, 0);
    }

#pragma unroll
    for (int i = 0; i < 2; i++) {
#pragma unroll
        for (int r = 0; r < 4; r++) {
            int grow = row0 + rb + i * 16 + (lane >> 4) * 4 + r;
            if (grow < NNODES) {
#pragma unroll
                for (int j = 0; j < 4; j++) {
                    int col = j * 16 + frow;
                    if (col < NCLS) {
                        size_t o = (size_t)grow * NCLS + col;
                        h2[o] = accum ? h2[o] + acc[i][j][r] : acc[i][j][r];
                    }
                }
            }
        }
    }
}

// ---------------- layer2 aggregation + bias -> out ----------------
__global__ __launch_bounds__(256) void k_agg2(const float* __restrict__ h2,
                                              const int* __restrict__ rowptr,
                                              const int* __restrict__ csr_src,
                                              const float* __restrict__ dinv,
                                              const float* __restrict__ b2c,
                                              void* out, const int* flags) {
    int v = blockIdx.x * 4 + (threadIdx.x >> 6);
    int d = threadIdx.x & 63;
    if (v >= NNODES || d >= NCLS) return;
    float dv = dinv[v];
    float acc = dv * dv * h2[(size_t)v * NCLS + d];
    int pend = rowptr[v + 1];
    for (int p = rowptr[v]; p < pend; ++p) {
        int u = csr_src[p];
        acc += dinv[u] * dv * h2[(size_t)u * NCLS + d];
    }
    acc += b2c[d];
    size_t o = (size_t)v * NCLS + d;
    if (flags[0]) ((bf16*)out)[o] = __float2bfloat16(acc);
    else          ((float*)out)[o] = acc;
}

extern "C" void kernel_launch(void* const* d_in, const int* in_sizes, int n_in,
                              void* d_out, int out_size, void* d_ws, size_t ws_size,
                              hipStream_t stream) {
    const void* x  = d_in[0];
    const void* ei = d_in[1];
    const void* W1 = d_in[2];
    const void* b1 = d_in[3];
    const void* W2 = d_in[4];
    const void* b2 = d_in[5];

    char* base = (char*)d_ws;
    auto alloc = [&](size_t bytes) -> char* {
        char* p = base;
        base += (bytes + 255) & ~(size_t)255;
        return p;
    };
    int*   flags  = (int*)alloc(64);
    int*   cnt    = (int*)alloc(sizeof(int) * NNODES);
    int*   part   = (int*)alloc(sizeof(int) * 256);
    int*   rowptr = (int*)alloc(sizeof(int) * (NNODES + 1));
    int*   cursor = (int*)alloc(sizeof(int) * NNODES);
    int*   csr    = (int*)alloc(sizeof(int) * NEDGES);
    float* dinv   = (float*)alloc(sizeof(float) * NNODES);
    bf16*  W1T    = (bf16*)alloc(sizeof(bf16) * DFEAT * HID);
    float* b1c    = (float*)alloc(sizeof(float) * HID);
    bf16*  W2T    = (bf16*)alloc(sizeof(bf16) * 64 * HID);
    float* b2c    = (float*)alloc(sizeof(float) * 64);
    float* h2     = (float*)alloc(sizeof(float) * (size_t)NNODES * NCLS);

    size_t used = (size_t)(base - (char*)d_ws);
    size_t rem = (ws_size > used) ? ws_size - used : 0;
    int C = 64;
    if (rem >= (size_t)200000 * 512 + 1024) C = 512;
    else if (rem >= (size_t)200000 * 256 + 1024) C = 256;
    else if (rem >= (size_t)200000 * 128 + 1024) C = 128;
    bf16* h1c = (bf16*)alloc(sizeof(bf16) * (size_t)NNODES * C);
    bf16* a1c = (bf16*)alloc(sizeof(bf16) * (size_t)NNODES * C);

    k_detect<<<1, 64, 0, stream>>>(x, ei, flags);
    k_zero32<<<(NNODES + 255) / 256, 256, 0, stream>>>((unsigned int*)cnt, NNODES);

    k_cvt_w1t<<<(DFEAT * HID + 255) / 256, 256, 0, stream>>>(W1, W1T, flags);
    k_cvt<<<(HID + 255) / 256, 256, 0, stream>>>(b1, b1c, HID, flags);
    k_cvt_w2t<<<(64 * HID + 255) / 256, 256, 0, stream>>>(W2, W2T, flags);
    k_cvt<<<1, 64, 0, stream>>>(b2, b2c, NCLS, flags);

    k_count<<<(NEDGES + 255) / 256, 256, 0, stream>>>(ei, cnt, flags);
    k_dinv<<<(NNODES + 255) / 256, 256, 0, stream>>>(cnt, dinv);
    const int nsb = (NNODES + 255) / 256;  // 196
    k_scan_part<<<nsb, 256, 0, stream>>>(cnt, part);
    k_scan_off<<<1, 256, 0, stream>>>(part, nsb);
    k_scan_fin<<<nsb, 256, 0, stream>>>(cnt, part, rowptr, cursor);
    k_fill<<<(NEDGES + 255) / 256, 256, 0, stream>>>(ei, cursor, csr, flags);

    const int rowblocks = (NNODES + 127) / 128;  // 391
    const int rows_per_xcd = (rowblocks + 7) / 8;  // 49
    int chunk_i = 0;
    for (int c0 = 0; c0 < HID; c0 += C, ++chunk_i) {
        if (C >= 128) {
            int col_tiles = C / 128;
            int nblk = 8 * rows_per_xcd * col_tiles;
            k_gemm1_v6<<<nblk, 256, 0, stream>>>(x, W1T, h1c, c0, C, flags,
                                                 col_tiles, rows_per_xcd, rowblocks);
        } else {
            dim3 g1(rowblocks, 1);
            k_gemm1_mfma<<<g1, 256, 0, stream>>>(x, W1T, h1c, c0, C, flags);
        }
        if (C == 512) {
            k_agg1_512<<<(NNODES + 3) / 4, 256, 0, stream>>>(h1c, rowptr, csr, dinv, b1c, a1c);
        } else {
            size_t nthr = (size_t)NNODES * (C / 4);
            k_agg1<<<(int)((nthr + 255) / 256), 256, 0, stream>>>(h1c, rowptr, csr, dinv, b1c, c0, C, a1c);
        }
        k_gemm2_v4<<<rowblocks, 256, 0, stream>>>(a1c, C, W2T, c0, h2, chunk_i > 0 ? 1 : 0);
    }

    k_agg2<<<(NNODES + 3) / 4, 256, 0, stream>>>(h2, rowptr, csr, dinv, b2c, d_out, flags);
}

// Round 4
// 413.395 us; speedup vs baseline: 1.0273x; 1.0273x over previous
//
#include <hip/hip_runtime.h>
#include <hip/hip_bf16.h>

#define NNODES 50000
#define NEDGES 150000
#define DFEAT  512
#define HID    512
#define NCLS   47

typedef __hip_bfloat16 bf16;
typedef __attribute__((ext_vector_type(8))) short short8;
typedef __attribute__((ext_vector_type(4))) float float4v;

typedef const __attribute__((address_space(1))) unsigned int* gas_t;
typedef __attribute__((address_space(3))) unsigned int* las_t;
__device__ __forceinline__ void load_lds16(const void* g, void* l) {
    __builtin_amdgcn_global_load_lds((gas_t)g, (las_t)l, 16, 0, 0);
}

__device__ __forceinline__ float bfbits_lo(unsigned int w) {
    return __uint_as_float((w & 0xFFFFu) << 16);
}
__device__ __forceinline__ float bfbits_hi(unsigned int w) {
    return __uint_as_float(w & 0xFFFF0000u);
}

// ---------------- dtype detection (1 block, 64 threads) ----------------
__global__ void k_detect(const void* x, const void* ei, int* flags) {
    __shared__ int scnt[64], sor[64];
    int t = threadIdx.x;
    const unsigned short* xs = (const unsigned short*)x;
    int c = 0;
    for (int i = t; i < 256; i += 64) {
        unsigned int e = (xs[2 * i] >> 7) & 0xFF;
        c += (e >= 117 && e <= 130) ? 1 : 0;
    }
    const int* w = (const int*)ei;
    int o = 0;
    for (int i = 2 * t + 1; i < 512; i += 128) o |= w[i];
    scnt[t] = c; sor[t] = o;
    __syncthreads();
    if (t == 0) {
        int C = 0, O = 0;
        for (int i = 0; i < 64; i++) { C += scnt[i]; O |= sor[i]; }
        flags[0] = (C > 128) ? 1 : 0;
        flags[1] = (O == 0) ? 1 : 0;
    }
}

__device__ __forceinline__ int eidx(const void* ei, int half, int e, int is64) {
    if (is64) return (int)((const long long*)ei)[(size_t)half * NEDGES + e];
    return ((const int*)ei)[half * NEDGES + e];
}

// ---------------- utility ----------------
__global__ void k_zero32(unsigned int* p, size_t n) {
    size_t i = (size_t)blockIdx.x * blockDim.x + threadIdx.x;
    if (i < n) p[i] = 0u;
}

__global__ void k_cvt(const void* src, float* dst, int n, const int* flags) {
    int i = blockIdx.x * blockDim.x + threadIdx.x;
    if (i >= n) return;
    dst[i] = flags[0] ? __bfloat162float(((const bf16*)src)[i]) : ((const float*)src)[i];
}

// W1 [K=512][N=512] -> W1T bf16 [N][K]
__global__ void k_cvt_w1t(const void* W1, bf16* W1T, const int* flags) {
    int i = blockIdx.x * blockDim.x + threadIdx.x;
    if (i >= DFEAT * HID) return;
    int k = i / HID, n = i % HID;
    float v = flags[0] ? __bfloat162float(((const bf16*)W1)[i]) : ((const float*)W1)[i];
    W1T[(size_t)n * DFEAT + k] = __float2bfloat16(v);
}

// W2 [K=512][N=47] -> W2T bf16 [64][512] zero-padded
__global__ void k_cvt_w2t(const void* W2, bf16* W2T, const int* flags) {
    int i = blockIdx.x * blockDim.x + threadIdx.x;
    if (i >= 64 * HID) return;
    int n = i / HID, k = i % HID;
    float v = 0.0f;
    if (n < NCLS) {
        size_t idx = (size_t)k * NCLS + n;
        v = flags[0] ? __bfloat162float(((const bf16*)W2)[idx]) : ((const float*)W2)[idx];
    }
    W2T[(size_t)n * HID + k] = __float2bfloat16(v);
}

// ---------------- graph structure ----------------
__global__ void k_count(const void* ei, int* cnt, const int* flags) {
    int e = blockIdx.x * blockDim.x + threadIdx.x;
    if (e >= NEDGES) return;
    atomicAdd(&cnt[eidx(ei, 1, e, flags[1])], 1);
}

__global__ void k_dinv(const int* cnt, float* dinv) {
    int i = blockIdx.x * blockDim.x + threadIdx.x;
    if (i < NNODES) dinv[i] = rsqrtf(1.0f + (float)cnt[i]);
}

__global__ __launch_bounds__(256) void k_scan_part(const int* cnt, int* part) {
    __shared__ int s[256];
    int i = blockIdx.x * 256 + threadIdx.x;
    s[threadIdx.x] = (i < NNODES) ? cnt[i] : 0;
    __syncthreads();
    for (int off = 128; off > 0; off >>= 1) {
        if (threadIdx.x < off) s[threadIdx.x] += s[threadIdx.x + off];
        __syncthreads();
    }
    if (threadIdx.x == 0) part[blockIdx.x] = s[0];
}

__global__ __launch_bounds__(256) void k_scan_off(int* part, int n) {
    __shared__ int s[256];
    int v = (threadIdx.x < n) ? part[threadIdx.x] : 0;
    s[threadIdx.x] = v;
    __syncthreads();
    for (int off = 1; off < 256; off <<= 1) {
        int t = (threadIdx.x >= off) ? s[threadIdx.x - off] : 0;
        __syncthreads();
        s[threadIdx.x] += t;
        __syncthreads();
    }
    if (threadIdx.x < n) part[threadIdx.x] = s[threadIdx.x] - v;
}

__global__ __launch_bounds__(256) void k_scan_fin(const int* cnt, const int* part,
                                                  int* rowptr, int* cursor) {
    __shared__ int s[256];
    int i = blockIdx.x * 256 + threadIdx.x;
    int v = (i < NNODES) ? cnt[i] : 0;
    s[threadIdx.x] = v;
    __syncthreads();
    for (int off = 1; off < 256; off <<= 1) {
        int t = (threadIdx.x >= off) ? s[threadIdx.x - off] : 0;
        __syncthreads();
        s[threadIdx.x] += t;
        __syncthreads();
    }
    int incl = s[threadIdx.x] + part[blockIdx.x];
    if (i < NNODES) {
        rowptr[i + 1] = incl;
        cursor[i] = incl - v;
    }
    if (i == 0) rowptr[0] = 0;
}

__global__ void k_fill(const void* ei, int* cursor, int* csr_src, const int* flags) {
    int e = blockIdx.x * blockDim.x + threadIdx.x;
    if (e >= NEDGES) return;
    int is64 = flags[1];
    int v = eidx(ei, 1, e, is64);
    int u = eidx(ei, 0, e, is64);
    int pos = atomicAdd(&cursor[v], 1);
    csr_src[pos] = u;
}

// ---------------- GEMM1 v7: BARRIER-FREE wave-private pipeline ----------------
// Block = 128 rows x 64 cols, 4 waves; each wave owns 32 rows x 64 cols.
// A staged via global_load_lds into a WAVE-PRIVATE triple-buffered LDS region
// (coalesced loads + fragment transpose via XOR-swizzle, zero VGPR cost,
// unlimited prefetch depth). Synchronization is per-wave counted
// s_waitcnt vmcnt only -- ZERO s_barrier in the kernel. Waves slip freely,
// so HBM latency overlaps across the 12 resident waves/CU.
// B (W1T) is read direct-to-register: 512 KB, permanently L2-resident; the
// 16 KB per-K-step slice is L1-hot and shared by all waves (v6 showed B
// gathers from L1 are cheap; only A gathers from HBM were the poison).
// vmcnt(16) proof (in-order retirement): at the wait of iter t the ops newer
// than stage(t) are >= {stage(t+1)[4], B(t)[8], stage(t+2)[4]} = 16, so
// <=16 outstanding implies stage(t) landed while both prefetched stages and
// B(t) may remain in flight. sched_barrier(0) pins the phase order so the
// count is exact.
__global__ __launch_bounds__(256, 3) void k_gemm1_v7(
    const void* __restrict__ X, const bf16* __restrict__ W1T,
    bf16* __restrict__ h1c, int c0, int C, const int* __restrict__ flags,
    int col_tiles, int rows_per_xcd, int n_row_tiles) {
    const int b = blockIdx.x;
    const int xcd = b & 7;
    const int s = b >> 3;
    const int col_t = s % col_tiles;
    const int lr = s / col_tiles;
    const int row_t = xcd * rows_per_xcd + lr;
    if (row_t >= n_row_tiles) return;

    __shared__ bf16 As[4][3][32 * 64];   // 4 waves x 3 buffers x 4 KiB = 48 KiB
    const int tid = threadIdx.x;
    const int wave = tid >> 6, lane = tid & 63;
    const int row0 = row_t * 128;
    const int gc0 = c0 + col_t * 64;
    const int isb = flags[0];

    const int rb = wave * 32;
    const int frow = lane & 15;
    const int fk = lane >> 4;

    float4v acc[2][4];
#pragma unroll
    for (int i = 0; i < 2; i++)
#pragma unroll
        for (int j = 0; j < 4; j++) acc[i][j] = (float4v){0.f, 0.f, 0.f, 0.f};

    // stage this wave's 32 rows x 64 cols (k0..k0+63) into buffer bi.
    // LDS[rl][p] = src[rl][p ^ (rl&7)]  (pre-swizzled source, linear dest)
    auto stageA = [&](int k0, int bi) {
        const bf16* xb = (const bf16*)X;
        bf16* dst = &As[wave][bi][0];
#pragma unroll
        for (int t = 0; t < 4; ++t) {
            int rl = t * 8 + (lane >> 3);            // 0..31
            int gr = row0 + rb + rl; if (gr >= NNODES) gr = NNODES - 1;
            int ck = (lane & 7) ^ (rl & 7);
            load_lds16(xb + (size_t)gr * DFEAT + k0 + ck * 8, dst + t * 8 * 64);
        }
    };

    if (isb) {
        stageA(0, 0);
        stageA(64, 1);
#pragma unroll
        for (int t = 0; t < 8; ++t) {
            const int k0 = t * 64;
            // --- B phase: 8 direct register loads (L1/L2-hot) ---
            short8 b8[2][4];
#pragma unroll
            for (int ki = 0; ki < 2; ++ki)
#pragma unroll
                for (int j = 0; j < 4; ++j)
                    b8[ki][j] = *(const short8*)(W1T +
                        (size_t)(gc0 + j * 16 + frow) * DFEAT + k0 + ki * 32 + fk * 8);
            __builtin_amdgcn_sched_barrier(0);
            // --- prefetch phase: stage A for step t+2 ---
            if (t + 2 < 8) stageA(k0 + 128, (t + 2) % 3);
            __builtin_amdgcn_sched_barrier(0);
            // --- per-wave wait: stage(t) landed; prefetch stays in flight ---
            asm volatile("s_waitcnt vmcnt(16)" ::: "memory");
            __builtin_amdgcn_sched_barrier(0);
            // --- compute phase ---
            const bf16* Ac = &As[wave][t % 3][0];
#pragma unroll
            for (int ki = 0; ki < 2; ++ki) {
                const int cc = ki * 4 + fk;
                short8 a[2];
#pragma unroll
                for (int i = 0; i < 2; i++) {
                    int rl = i * 16 + frow;
                    a[i] = *(const short8*)&Ac[rl * 64 + (cc ^ (rl & 7)) * 8];
                }
#pragma unroll
                for (int i = 0; i < 2; i++)
#pragma unroll
                    for (int j = 0; j < 4; j++)
                        acc[i][j] = __builtin_amdgcn_mfma_f32_16x16x32_bf16(a[i], b8[ki][j], acc[i][j], 0, 0, 0);
            }
        }
    } else {
        // f32 fallback: wave-private single-buffer LDS staging via ds_write
        // (same-wave LDS ops are in-order; no sync needed). Correctness path.
        const float* xf = (const float*)X;
        for (int t = 0; t < 8; ++t) {
            const int k0 = t * 64;
            bf16* dst = &As[wave][0][0];
            int rl = lane >> 1;
            int gr = row0 + rb + rl; if (gr >= NNODES) gr = NNODES - 1;
#pragma unroll
            for (int pp = 0; pp < 4; ++pp) {
                int p = (lane & 1) * 4 + pp;
                const float* src = xf + (size_t)gr * DFEAT + k0 + ((p ^ (rl & 7)) * 8);
#pragma unroll
                for (int e = 0; e < 8; ++e)
                    dst[rl * 64 + p * 8 + e] = __float2bfloat16(src[e]);
            }
            short8 b8[2][4];
#pragma unroll
            for (int ki = 0; ki < 2; ++ki)
#pragma unroll
                for (int j = 0; j < 4; ++j)
                    b8[ki][j] = *(const short8*)(W1T +
                        (size_t)(gc0 + j * 16 + frow) * DFEAT + k0 + ki * 32 + fk * 8);
#pragma unroll
            for (int ki = 0; ki < 2; ++ki) {
                const int cc = ki * 4 + fk;
                short8 a[2];
#pragma unroll
                for (int i = 0; i < 2; i++) {
                    int rl2 = i * 16 + frow;
                    a[i] = *(const short8*)&dst[rl2 * 64 + (cc ^ (rl2 & 7)) * 8];
                }
#pragma unroll
                for (int i = 0; i < 2; i++)
#pragma unroll
                    for (int j = 0; j < 4; j++)
                        acc[i][j] = __builtin_amdgcn_mfma_f32_16x16x32_bf16(a[i], b8[ki][j], acc[i][j], 0, 0, 0);
            }
        }
    }

    const int ccol0 = (gc0 - c0);
#pragma unroll
    for (int i = 0; i < 2; i++) {
#pragma unroll
        for (int r = 0; r < 4; r++) {
            int grow = row0 + rb + i * 16 + (lane >> 4) * 4 + r;
            if (grow < NNODES) {
#pragma unroll
                for (int j = 0; j < 4; j++)
                    h1c[(size_t)grow * C + ccol0 + j * 16 + frow] =
                        __float2bfloat16(acc[i][j][r]);
            }
        }
    }
}

// ---------------- layer1 aggregation, C=512: one wave per node, uint4 loads ----
__global__ __launch_bounds__(256) void k_agg1_512(const bf16* __restrict__ h1c,
                                                  const int* __restrict__ rowptr,
                                                  const int* __restrict__ csr_src,
                                                  const float* __restrict__ dinv,
                                                  const float* __restrict__ b1c,
                                                  bf16* __restrict__ a1c) {
    int v = blockIdx.x * 4 + (threadIdx.x >> 6);
    int lane = threadIdx.x & 63;
    if (v >= NNODES) return;
    int d8 = lane * 8;
    float dv = dinv[v];
    float s2 = dv * dv;
    uint4 w = *(const uint4*)(h1c + (size_t)v * 512 + d8);
    float a0 = s2 * bfbits_lo(w.x), a1 = s2 * bfbits_hi(w.x);
    float a2 = s2 * bfbits_lo(w.y), a3 = s2 * bfbits_hi(w.y);
    float a4 = s2 * bfbits_lo(w.z), a5 = s2 * bfbits_hi(w.z);
    float a6 = s2 * bfbits_lo(w.w), a7 = s2 * bfbits_hi(w.w);
    int pend = rowptr[v + 1];
    for (int p = rowptr[v]; p < pend; ++p) {
        int u = csr_src[p];
        float nw = dinv[u] * dv;
        uint4 q = *(const uint4*)(h1c + (size_t)u * 512 + d8);
        a0 += nw * bfbits_lo(q.x); a1 += nw * bfbits_hi(q.x);
        a2 += nw * bfbits_lo(q.y); a3 += nw * bfbits_hi(q.y);
        a4 += nw * bfbits_lo(q.z); a5 += nw * bfbits_hi(q.z);
        a6 += nw * bfbits_lo(q.w); a7 += nw * bfbits_hi(q.w);
    }
    const float* bb = b1c + d8;
    a0 += bb[0]; a1 += bb[1]; a2 += bb[2]; a3 += bb[3];
    a4 += bb[4]; a5 += bb[5]; a6 += bb[6]; a7 += bb[7];
    bf16 o[8];
    o[0] = __float2bfloat16(a0 > 0.f ? a0 : 0.f);
    o[1] = __float2bfloat16(a1 > 0.f ? a1 : 0.f);
    o[2] = __float2bfloat16(a2 > 0.f ? a2 : 0.f);
    o[3] = __float2bfloat16(a3 > 0.f ? a3 : 0.f);
    o[4] = __float2bfloat16(a4 > 0.f ? a4 : 0.f);
    o[5] = __float2bfloat16(a5 > 0.f ? a5 : 0.f);
    o[6] = __float2bfloat16(a6 > 0.f ? a6 : 0.f);
    o[7] = __float2bfloat16(a7 > 0.f ? a7 : 0.f);
    *(uint4*)(a1c + (size_t)v * 512 + d8) = *(uint4*)o;
}

// ---------------- layer1 aggregation, generic ----------------
__global__ __launch_bounds__(256) void k_agg1(const bf16* __restrict__ h1c,
                                              const int* __restrict__ rowptr,
                                              const int* __restrict__ csr_src,
                                              const float* __restrict__ dinv,
                                              const float* __restrict__ b1c, int c0, int C,
                                              bf16* __restrict__ a1c) {
    const int tshift = (C == 512) ? 7 : (C == 256) ? 6 : (C == 128) ? 5 : 4;
    long long gt = (long long)blockIdx.x * 256 + threadIdx.x;
    int v = (int)(gt >> tshift);
    int d4 = (int)((gt & ((1 << tshift) - 1)) << 2);
    if (v >= NNODES) return;
    float dv = dinv[v];
    uint2 w = *(const uint2*)(h1c + (size_t)v * C + d4);
    float s2 = dv * dv;
    float a0 = s2 * bfbits_lo(w.x), a1 = s2 * bfbits_hi(w.x);
    float a2 = s2 * bfbits_lo(w.y), a3 = s2 * bfbits_hi(w.y);
    int pend = rowptr[v + 1];
    for (int p = rowptr[v]; p < pend; ++p) {
        int u = csr_src[p];
        float nw = dinv[u] * dv;
        uint2 q = *(const uint2*)(h1c + (size_t)u * C + d4);
        a0 += nw * bfbits_lo(q.x); a1 += nw * bfbits_hi(q.x);
        a2 += nw * bfbits_lo(q.y); a3 += nw * bfbits_hi(q.y);
    }
    const float* bb = b1c + c0 + d4;
    a0 += bb[0]; a1 += bb[1]; a2 += bb[2]; a3 += bb[3];
    bf16 o[4];
    o[0] = __float2bfloat16(a0 > 0.f ? a0 : 0.f);
    o[1] = __float2bfloat16(a1 > 0.f ? a1 : 0.f);
    o[2] = __float2bfloat16(a2 > 0.f ? a2 : 0.f);
    o[3] = __float2bfloat16(a3 > 0.f ? a3 : 0.f);
    *(uint2*)(a1c + (size_t)v * C + d4) = *(uint2*)o;
}

// ---------------- GEMM2 v2: 2-phase double-buffer + XOR-swizzled LDS ----------
__global__ __launch_bounds__(256, 3) void k_gemm2_v2(
    const bf16* __restrict__ A, int C, const bf16* __restrict__ W2T, int kg0,
    float* __restrict__ h2, int accum) {
    __shared__ bf16 As[2][128 * 64];   // 2 x 16 KiB
    __shared__ bf16 Bs[2][64 * 64];    // 2 x  8 KiB  -> 48 KiB, 3 blocks/CU
    const int tid = threadIdx.x;
    const int wave = tid >> 6, lane = tid & 63;
    const int row0 = blockIdx.x * 128;
    float4v acc[2][4];
#pragma unroll
    for (int i = 0; i < 2; i++)
#pragma unroll
        for (int j = 0; j < 4; j++) acc[i][j] = (float4v){0.f, 0.f, 0.f, 0.f};
    const int rb = wave * 32;
    const int frow = lane & 15;
    const int fk = lane >> 4;

    auto stage2 = [&](int kk, bf16* Asb, bf16* Bsb) {
#pragma unroll
        for (int t = 0; t < 4; ++t) {
            int g8 = wave * 4 + t;
            int r = g8 * 8 + (lane >> 3);
            int gr = row0 + r; if (gr >= NNODES) gr = NNODES - 1;
            int ck = (lane & 7) ^ (r & 7);
            load_lds16(A + (size_t)gr * C + kk + ck * 8, Asb + g8 * 8 * 64);
        }
#pragma unroll
        for (int t = 0; t < 2; ++t) {
            int g8 = wave * 2 + t;
            int cl = g8 * 8 + (lane >> 3);
            int ck = (lane & 7) ^ (cl & 7);
            load_lds16(W2T + (size_t)cl * HID + kg0 + kk + ck * 8, Bsb + g8 * 8 * 64);
        }
    };

    stage2(0, As[0], Bs[0]);
    __syncthreads();
    int cur = 0;

    for (int kk = 0; kk < C; kk += 64) {
        if (kk + 64 < C) stage2(kk + 64, As[cur ^ 1], Bs[cur ^ 1]);
        const bf16* Ac = As[cur];
        const bf16* Bc = Bs[cur];
#pragma unroll
        for (int ki = 0; ki < 2; ++ki) {
            const int cc = ki * 4 + fk;
            short8 a[2], b8[4];
#pragma unroll
            for (int i = 0; i < 2; i++) {
                int r = rb + i * 16 + frow;
                a[i] = *(const short8*)&Ac[r * 64 + (cc ^ (r & 7)) * 8];
            }
#pragma unroll
            for (int j = 0; j < 4; j++) {
                int cl = j * 16 + frow;
                b8[j] = *(const short8*)&Bc[cl * 64 + (cc ^ (cl & 7)) * 8];
            }
#pragma unroll
            for (int i = 0; i < 2; i++)
#pragma unroll
                for (int j = 0; j < 4; j++)
                    acc[i][j] = __builtin_amdgcn_mfma_f32_16x16x32_bf16(a[i], b8[j], acc[i][j], 0, 0, 0);
        }
        __syncthreads();
        cur ^= 1;
    }
#pragma unroll
    for (int i = 0; i < 2; i++) {
#pragma unroll
        for (int r = 0; r < 4; r++) {
            int grow = row0 + rb + i * 16 + (lane >> 4) * 4 + r;
            if (grow < NNODES) {
#pragma unroll
                for (int j = 0; j < 4; j++) {
                    int col = j * 16 + frow;
                    if (col < NCLS) {
                        size_t o = (size_t)grow * NCLS + col;
                        h2[o] = accum ? h2[o] + acc[i][j][r] : acc[i][j][r];
                    }
                }
            }
        }
    }
}

// ---------------- layer2 aggregation + bias -> out ----------------
__global__ __launch_bounds__(256) void k_agg2(const float* __restrict__ h2,
                                              const int* __restrict__ rowptr,
                                              const int* __restrict__ csr_src,
                                              const float* __restrict__ dinv,
                                              const float* __restrict__ b2c,
                                              void* out, const int* flags) {
    int v = blockIdx.x * 4 + (threadIdx.x >> 6);
    int d = threadIdx.x & 63;
    if (v >= NNODES || d >= NCLS) return;
    float dv = dinv[v];
    float acc = dv * dv * h2[(size_t)v * NCLS + d];
    int pend = rowptr[v + 1];
    for (int p = rowptr[v]; p < pend; ++p) {
        int u = csr_src[p];
        acc += dinv[u] * dv * h2[(size_t)u * NCLS + d];
    }
    acc += b2c[d];
    size_t o = (size_t)v * NCLS + d;
    if (flags[0]) ((bf16*)out)[o] = __float2bfloat16(acc);
    else          ((float*)out)[o] = acc;
}

extern "C" void kernel_launch(void* const* d_in, const int* in_sizes, int n_in,
                              void* d_out, int out_size, void* d_ws, size_t ws_size,
                              hipStream_t stream) {
    const void* x  = d_in[0];
    const void* ei = d_in[1];
    const void* W1 = d_in[2];
    const void* b1 = d_in[3];
    const void* W2 = d_in[4];
    const void* b2 = d_in[5];

    char* base = (char*)d_ws;
    auto alloc = [&](size_t bytes) -> char* {
        char* p = base;
        base += (bytes + 255) & ~(size_t)255;
        return p;
    };
    int*   flags  = (int*)alloc(64);
    int*   cnt    = (int*)alloc(sizeof(int) * NNODES);
    int*   part   = (int*)alloc(sizeof(int) * 256);
    int*   rowptr = (int*)alloc(sizeof(int) * (NNODES + 1));
    int*   cursor = (int*)alloc(sizeof(int) * NNODES);
    int*   csr    = (int*)alloc(sizeof(int) * NEDGES);
    float* dinv   = (float*)alloc(sizeof(float) * NNODES);
    bf16*  W1T    = (bf16*)alloc(sizeof(bf16) * DFEAT * HID);
    float* b1c    = (float*)alloc(sizeof(float) * HID);
    bf16*  W2T    = (bf16*)alloc(sizeof(bf16) * 64 * HID);
    float* b2c    = (float*)alloc(sizeof(float) * 64);
    float* h2     = (float*)alloc(sizeof(float) * (size_t)NNODES * NCLS);

    size_t used = (size_t)(base - (char*)d_ws);
    size_t rem = (ws_size > used) ? ws_size - used : 0;
    int C = 64;
    if (rem >= (size_t)200000 * 512 + 1024) C = 512;
    else if (rem >= (size_t)200000 * 256 + 1024) C = 256;
    else if (rem >= (size_t)200000 * 128 + 1024) C = 128;
    bf16* h1c = (bf16*)alloc(sizeof(bf16) * (size_t)NNODES * C);
    bf16* a1c = (bf16*)alloc(sizeof(bf16) * (size_t)NNODES * C);

    k_detect<<<1, 64, 0, stream>>>(x, ei, flags);
    k_zero32<<<(NNODES + 255) / 256, 256, 0, stream>>>((unsigned int*)cnt, NNODES);

    k_cvt_w1t<<<(DFEAT * HID + 255) / 256, 256, 0, stream>>>(W1, W1T, flags);
    k_cvt<<<(HID + 255) / 256, 256, 0, stream>>>(b1, b1c, HID, flags);
    k_cvt_w2t<<<(64 * HID + 255) / 256, 256, 0, stream>>>(W2, W2T, flags);
    k_cvt<<<1, 64, 0, stream>>>(b2, b2c, NCLS, flags);

    k_count<<<(NEDGES + 255) / 256, 256, 0, stream>>>(ei, cnt, flags);
    k_dinv<<<(NNODES + 255) / 256, 256, 0, stream>>>(cnt, dinv);
    const int nsb = (NNODES + 255) / 256;  // 196
    k_scan_part<<<nsb, 256, 0, stream>>>(cnt, part);
    k_scan_off<<<1, 256, 0, stream>>>(part, nsb);
    k_scan_fin<<<nsb, 256, 0, stream>>>(cnt, part, rowptr, cursor);
    k_fill<<<(NEDGES + 255) / 256, 256, 0, stream>>>(ei, cursor, csr, flags);

    const int rowblocks = (NNODES + 127) / 128;  // 391
    const int rows_per_xcd = (rowblocks + 7) / 8;  // 49
    int chunk_i = 0;
    for (int c0 = 0; c0 < HID; c0 += C, ++chunk_i) {
        {
            int col_tiles = C / 64;   // 64-col tiles for v7
            int nblk = 8 * rows_per_xcd * col_tiles;
            k_gemm1_v7<<<nblk, 256, 0, stream>>>(x, W1T, h1c, c0, C, flags,
                                                 col_tiles, rows_per_xcd, rowblocks);
        }
        if (C == 512) {
            k_agg1_512<<<(NNODES + 3) / 4, 256, 0, stream>>>(h1c, rowptr, csr, dinv, b1c, a1c);
        } else {
            size_t nthr = (size_t)NNODES * (C / 4);
            k_agg1<<<(int)((nthr + 255) / 256), 256, 0, stream>>>(h1c, rowptr, csr, dinv, b1c, c0, C, a1c);
        }
        k_gemm2_v2<<<rowblocks, 256, 0, stream>>>(a1c, C, W2T, c0, h2, chunk_i > 0 ? 1 : 0);
    }

    k_agg2<<<(NNODES + 3) / 4, 256, 0, stream>>>(h2, rowptr, csr, dinv, b2c, d_out, flags);
}

// Round 5
// 336.172 us; speedup vs baseline: 1.2633x; 1.2297x over previous
//
#include <hip/hip_runtime.h>
#include <hip/hip_bf16.h>

#define NNODES 50000
#define NEDGES 150000
#define DFEAT  512
#define HID    512
#define NCLS   47

typedef __hip_bfloat16 bf16;
typedef __attribute__((ext_vector_type(8))) short short8;
typedef __attribute__((ext_vector_type(4))) float float4v;

typedef const __attribute__((address_space(1))) unsigned int* gas_t;
typedef __attribute__((address_space(3))) unsigned int* las_t;
__device__ __forceinline__ void load_lds16(const void* g, void* l) {
    __builtin_amdgcn_global_load_lds((gas_t)g, (las_t)l, 16, 0, 0);
}

__device__ __forceinline__ float bfbits_lo(unsigned int w) {
    return __uint_as_float((w & 0xFFFFu) << 16);
}
__device__ __forceinline__ float bfbits_hi(unsigned int w) {
    return __uint_as_float(w & 0xFFFF0000u);
}

__device__ __forceinline__ int eidx(const void* ei, int half, int e, int is64) {
    if (is64) return (int)((const long long*)ei)[(size_t)half * NEDGES + e];
    return ((const int*)ei)[half * NEDGES + e];
}

// ---------------- fused prep kernel: role-dispatched by blockIdx ----------------
// roles: [0] detect->flags   [1,1+ZB) zero cnt   [w1t: 1024 blocks]
//        [b1: 2 blocks]      [w2t: 128 blocks]   [b2: 1 block]
// cvt roles re-derive the bf16 flag locally (256-sample exponent scan) since
// block execution order within a kernel is undefined.
#define ZB ((NNODES + 255) / 256)
#define PR_W1T (1 + ZB)
#define PR_B1  (PR_W1T + 1024)
#define PR_W2T (PR_B1 + 2)
#define PR_B2  (PR_W2T + 128)
#define PR_GRID (PR_B2 + 1)

__global__ __launch_bounds__(256) void k_prep0(
    const void* x, const void* ei, const void* W1, const void* b1,
    const void* W2, const void* b2, int* flags, unsigned int* cnt,
    bf16* W1T, float* b1c, bf16* W2T, float* b2c) {
    __shared__ int sh[128];
    __shared__ int shflag;
    const int b = blockIdx.x, t = threadIdx.x;

    if (b >= 1 && b < 1 + ZB) {              // zero cnt
        int i = (b - 1) * 256 + t;
        if (i < NNODES) cnt[i] = 0u;
        return;
    }

    // local bf16 detection (all non-zero roles need it; role 0 also writes flags)
    if (t < 64) {
        const unsigned short* xs = (const unsigned short*)x;
        int c = 0;
        for (int i = t; i < 256; i += 64) {
            unsigned int e = (xs[2 * i] >> 7) & 0xFF;
            c += (e >= 117 && e <= 130) ? 1 : 0;
        }
        sh[t] = c;
        if (b == 0) {
            const int* w = (const int*)ei;
            int o = 0;
            for (int i = 2 * t + 1; i < 512; i += 128) o |= w[i];
            sh[64 + t] = o;
        }
    }
    __syncthreads();
    if (t == 0) {
        int C = 0;
        for (int i = 0; i < 64; i++) C += sh[i];
        shflag = (C > 128) ? 1 : 0;
        if (b == 0) {
            int O = 0;
            for (int i = 0; i < 64; i++) O |= sh[64 + i];
            flags[0] = shflag;
            flags[1] = (O == 0) ? 1 : 0;
        }
    }
    __syncthreads();
    const int isb = shflag;

    if (b == 0) return;

    if (b >= PR_W1T && b < PR_B1) {          // W1 [K][N] -> W1T bf16 [N][K]
        int i = (b - PR_W1T) * 256 + t;
        int k = i / HID, n = i % HID;
        float v = isb ? __bfloat162float(((const bf16*)W1)[i]) : ((const float*)W1)[i];
        W1T[(size_t)n * DFEAT + k] = __float2bfloat16(v);
    } else if (b >= PR_B1 && b < PR_W2T) {   // b1 -> f32
        int i = (b - PR_B1) * 256 + t;
        if (i < HID)
            b1c[i] = isb ? __bfloat162float(((const bf16*)b1)[i]) : ((const float*)b1)[i];
    } else if (b >= PR_W2T && b < PR_B2) {   // W2 [K][47] -> W2T bf16 [64][512] pad
        int i = (b - PR_W2T) * 256 + t;
        int n = i / HID, k = i % HID;
        float v = 0.0f;
        if (n < NCLS) {
            size_t idx = (size_t)k * NCLS + n;
            v = isb ? __bfloat162float(((const bf16*)W2)[idx]) : ((const float*)W2)[idx];
        }
        W2T[(size_t)n * HID + k] = __float2bfloat16(v);
    } else if (b == PR_B2) {                 // b2 -> f32
        if (t < NCLS)
            b2c[t] = isb ? __bfloat162float(((const bf16*)b2)[t]) : ((const float*)b2)[t];
    }
}

// ---------------- graph structure ----------------
__global__ void k_count(const void* ei, int* cnt, const int* flags) {
    int e = blockIdx.x * blockDim.x + threadIdx.x;
    if (e >= NEDGES) return;
    atomicAdd(&cnt[eidx(ei, 1, e, flags[1])], 1);
}

__global__ __launch_bounds__(256) void k_scan_part_dinv(const int* cnt, int* part,
                                                        float* dinv) {
    __shared__ int s[256];
    int i = blockIdx.x * 256 + threadIdx.x;
    int v = (i < NNODES) ? cnt[i] : 0;
    if (i < NNODES) dinv[i] = rsqrtf(1.0f + (float)v);
    s[threadIdx.x] = v;
    __syncthreads();
    for (int off = 128; off > 0; off >>= 1) {
        if (threadIdx.x < off) s[threadIdx.x] += s[threadIdx.x + off];
        __syncthreads();
    }
    if (threadIdx.x == 0) part[blockIdx.x] = s[0];
}

__global__ __launch_bounds__(256) void k_scan_off(int* part, int n) {
    __shared__ int s[256];
    int v = (threadIdx.x < n) ? part[threadIdx.x] : 0;
    s[threadIdx.x] = v;
    __syncthreads();
    for (int off = 1; off < 256; off <<= 1) {
        int t = (threadIdx.x >= off) ? s[threadIdx.x - off] : 0;
        __syncthreads();
        s[threadIdx.x] += t;
        __syncthreads();
    }
    if (threadIdx.x < n) part[threadIdx.x] = s[threadIdx.x] - v;
}

__global__ __launch_bounds__(256) void k_scan_fin(const int* cnt, const int* part,
                                                  int* rowptr, int* cursor) {
    __shared__ int s[256];
    int i = blockIdx.x * 256 + threadIdx.x;
    int v = (i < NNODES) ? cnt[i] : 0;
    s[threadIdx.x] = v;
    __syncthreads();
    for (int off = 1; off < 256; off <<= 1) {
        int t = (threadIdx.x >= off) ? s[threadIdx.x - off] : 0;
        __syncthreads();
        s[threadIdx.x] += t;
        __syncthreads();
    }
    int incl = s[threadIdx.x] + part[blockIdx.x];
    if (i < NNODES) {
        rowptr[i + 1] = incl;
        cursor[i] = incl - v;
    }
    if (i == 0) rowptr[0] = 0;
}

__global__ void k_fill(const void* ei, int* cursor, int* csr_src, const int* flags) {
    int e = blockIdx.x * blockDim.x + threadIdx.x;
    if (e >= NEDGES) return;
    int is64 = flags[1];
    int v = eidx(ei, 1, e, is64);
    int u = eidx(ei, 0, e, is64);
    int pos = atomicAdd(&cursor[v], 1);
    csr_src[pos] = u;
}

// ---------------- GEMM1 v3 (round-0 best: 109 us) ----------------
// 128x128, XOR-swizzled LDS, XCD-aware remap, single-buffer 2-barrier loop.
__global__ __launch_bounds__(256, 3) void k_gemm1_v3(
    const void* __restrict__ X, const bf16* __restrict__ W1T,
    bf16* __restrict__ h1c, int c0, int C, const int* __restrict__ flags,
    int col_tiles, int rows_per_xcd, int n_row_tiles) {
    const int b = blockIdx.x;
    const int xcd = b & 7;
    const int s = b >> 3;
    const int col_t = s % col_tiles;
    const int lr = s / col_tiles;
    const int row_t = xcd * rows_per_xcd + lr;
    if (row_t >= n_row_tiles) return;

    __shared__ bf16 As[128 * 64];
    __shared__ bf16 Bs[128 * 64];
    const int tid = threadIdx.x;
    const int wave = tid >> 6, lane = tid & 63;
    const int row0 = row_t * 128;
    const int gc0 = c0 + col_t * 128;
    const int isb = flags[0];

    float4v acc[2][8];
#pragma unroll
    for (int i = 0; i < 2; i++)
#pragma unroll
        for (int j = 0; j < 8; j++) acc[i][j] = (float4v){0.f, 0.f, 0.f, 0.f};

    const int rb = wave * 32;
    const int frow = lane & 15;
    const int fk = lane >> 4;

    for (int k0 = 0; k0 < DFEAT; k0 += 64) {
        __syncthreads();
        if (isb) {
            const bf16* xb = (const bf16*)X;
#pragma unroll
            for (int t = 0; t < 4; ++t) {
                int g8 = wave * 4 + t;
                int r = g8 * 8 + (lane >> 3);
                int gr = row0 + r; if (gr >= NNODES) gr = NNODES - 1;
                int ck = (lane & 7) ^ (r & 7);
                load_lds16(xb + (size_t)gr * DFEAT + k0 + ck * 8, &As[g8 * 8 * 64]);
            }
        } else {
            const float* xf = (const float*)X;
            for (int i = tid; i < 128 * 8; i += 256) {
                int r = i >> 3, p = i & 7;
                int gr = row0 + r; if (gr >= NNODES) gr = NNODES - 1;
                int ck = p ^ (r & 7);
                const float* src = xf + (size_t)gr * DFEAT + k0 + ck * 8;
#pragma unroll
                for (int e = 0; e < 8; ++e)
                    As[r * 64 + p * 8 + e] = __float2bfloat16(src[e]);
            }
        }
#pragma unroll
        for (int t = 0; t < 4; ++t) {
            int g8 = wave * 4 + t;
            int cl = g8 * 8 + (lane >> 3);
            int ck = (lane & 7) ^ (cl & 7);
            load_lds16(W1T + (size_t)(gc0 + cl) * DFEAT + k0 + ck * 8, &Bs[g8 * 8 * 64]);
        }
        __syncthreads();
#pragma unroll
        for (int ki = 0; ki < 2; ++ki) {
            const int cc = ki * 4 + fk;
            short8 a[2], b8[8];
#pragma unroll
            for (int i = 0; i < 2; i++) {
                int r = rb + i * 16 + frow;
                a[i] = *(const short8*)&As[r * 64 + (cc ^ (r & 7)) * 8];
            }
#pragma unroll
            for (int j = 0; j < 8; j++) {
                int cl = j * 16 + frow;
                b8[j] = *(const short8*)&Bs[cl * 64 + (cc ^ (cl & 7)) * 8];
            }
#pragma unroll
            for (int i = 0; i < 2; i++)
#pragma unroll
                for (int j = 0; j < 8; j++)
                    acc[i][j] = __builtin_amdgcn_mfma_f32_16x16x32_bf16(a[i], b8[j], acc[i][j], 0, 0, 0);
        }
    }
    const int ccol = gc0 - c0;
#pragma unroll
    for (int i = 0; i < 2; i++) {
#pragma unroll
        for (int r = 0; r < 4; r++) {
            int grow = row0 + rb + i * 16 + (lane >> 4) * 4 + r;
            if (grow < NNODES) {
#pragma unroll
                for (int j = 0; j < 8; j++)
                    h1c[(size_t)grow * C + ccol + j * 16 + (lane & 15)] =
                        __float2bfloat16(acc[i][j][r]);
            }
        }
    }
}

// ---------------- legacy GEMM1 (C==64 fallback) ----------------
__global__ __launch_bounds__(256) void k_gemm1_mfma(
    const void* __restrict__ X, const bf16* __restrict__ W1T,
    bf16* __restrict__ h1c, int c0, int C, const int* __restrict__ flags) {
    __shared__ bf16 As[128 * 64];
    __shared__ bf16 Bs[64 * 64];
    const int tid = threadIdx.x;
    const int wave = tid >> 6, lane = tid & 63;
    const int row0 = blockIdx.x * 128;
    const int gc0 = c0 + blockIdx.y * 64;
    const int isb = flags[0];
    float4v acc[2][4];
#pragma unroll
    for (int i = 0; i < 2; i++)
#pragma unroll
        for (int j = 0; j < 4; j++) acc[i][j] = (float4v){0.f, 0.f, 0.f, 0.f};
    const int rbase = wave * 32;
    const int fl_row = lane & 15;
    const int fl_k8 = (lane >> 4) * 8;
    for (int k0 = 0; k0 < DFEAT; k0 += 64) {
        __syncthreads();
        if (isb) {
            const bf16* xb = (const bf16*)X;
#pragma unroll
            for (int i = 0; i < 4; ++i) {
                int r = i * 32 + wave * 8;
                int gr = row0 + r + (lane >> 3);
                if (gr >= NNODES) gr = NNODES - 1;
                load_lds16(xb + (size_t)gr * DFEAT + k0 + (lane & 7) * 8, &As[r * 64]);
            }
        } else {
            const float* xf = (const float*)X;
            for (int i = tid; i < 128 * 64; i += 256) {
                int r = i >> 6, c = i & 63;
                int gr = row0 + r;
                if (gr >= NNODES) gr = NNODES - 1;
                As[i] = __float2bfloat16(xf[(size_t)gr * DFEAT + k0 + c]);
            }
        }
#pragma unroll
        for (int i = 0; i < 2; ++i) {
            int r = i * 32 + wave * 8;
            int gn = gc0 + r + (lane >> 3);
            load_lds16(W1T + (size_t)gn * DFEAT + k0 + (lane & 7) * 8, &Bs[r * 64]);
        }
        __syncthreads();
#pragma unroll
        for (int ki = 0; ki < 64; ki += 32) {
            short8 a[2], b[4];
#pragma unroll
            for (int i = 0; i < 2; i++)
                a[i] = *(const short8*)&As[(rbase + i * 16 + fl_row) * 64 + ki + fl_k8];
#pragma unroll
            for (int j = 0; j < 4; j++)
                b[j] = *(const short8*)&Bs[(j * 16 + fl_row) * 64 + ki + fl_k8];
#pragma unroll
            for (int i = 0; i < 2; i++)
#pragma unroll
                for (int j = 0; j < 4; j++)
                    acc[i][j] = __builtin_amdgcn_mfma_f32_16x16x32_bf16(a[i], b[j], acc[i][j], 0, 0, 0);
        }
    }
    const int ccol = blockIdx.y * 64;
#pragma unroll
    for (int i = 0; i < 2; i++) {
#pragma unroll
        for (int r = 0; r < 4; r++) {
            int grow = row0 + rbase + i * 16 + (lane >> 4) * 4 + r;
            if (grow < NNODES) {
#pragma unroll
                for (int j = 0; j < 4; j++)
                    h1c[(size_t)grow * C + ccol + j * 16 + (lane & 15)] =
                        __float2bfloat16(acc[i][j][r]);
            }
        }
    }
}

// ---------------- layer1 aggregation, C=512: one wave per node ----------------
__global__ __launch_bounds__(256) void k_agg1_512(const bf16* __restrict__ h1c,
                                                  const int* __restrict__ rowptr,
                                                  const int* __restrict__ csr_src,
                                                  const float* __restrict__ dinv,
                                                  const float* __restrict__ b1c,
                                                  bf16* __restrict__ a1c) {
    int v = blockIdx.x * 4 + (threadIdx.x >> 6);
    int lane = threadIdx.x & 63;
    if (v >= NNODES) return;
    int d8 = lane * 8;
    float dv = dinv[v];
    float s2 = dv * dv;
    uint4 w = *(const uint4*)(h1c + (size_t)v * 512 + d8);
    float a0 = s2 * bfbits_lo(w.x), a1 = s2 * bfbits_hi(w.x);
    float a2 = s2 * bfbits_lo(w.y), a3 = s2 * bfbits_hi(w.y);
    float a4 = s2 * bfbits_lo(w.z), a5 = s2 * bfbits_hi(w.z);
    float a6 = s2 * bfbits_lo(w.w), a7 = s2 * bfbits_hi(w.w);
    int pend = rowptr[v + 1];
    for (int p = rowptr[v]; p < pend; ++p) {
        int u = csr_src[p];
        float nw = dinv[u] * dv;
        uint4 q = *(const uint4*)(h1c + (size_t)u * 512 + d8);
        a0 += nw * bfbits_lo(q.x); a1 += nw * bfbits_hi(q.x);
        a2 += nw * bfbits_lo(q.y); a3 += nw * bfbits_hi(q.y);
        a4 += nw * bfbits_lo(q.z); a5 += nw * bfbits_hi(q.z);
        a6 += nw * bfbits_lo(q.w); a7 += nw * bfbits_hi(q.w);
    }
    const float* bb = b1c + d8;
    a0 += bb[0]; a1 += bb[1]; a2 += bb[2]; a3 += bb[3];
    a4 += bb[4]; a5 += bb[5]; a6 += bb[6]; a7 += bb[7];
    bf16 o[8];
    o[0] = __float2bfloat16(a0 > 0.f ? a0 : 0.f);
    o[1] = __float2bfloat16(a1 > 0.f ? a1 : 0.f);
    o[2] = __float2bfloat16(a2 > 0.f ? a2 : 0.f);
    o[3] = __float2bfloat16(a3 > 0.f ? a3 : 0.f);
    o[4] = __float2bfloat16(a4 > 0.f ? a4 : 0.f);
    o[5] = __float2bfloat16(a5 > 0.f ? a5 : 0.f);
    o[6] = __float2bfloat16(a6 > 0.f ? a6 : 0.f);
    o[7] = __float2bfloat16(a7 > 0.f ? a7 : 0.f);
    *(uint4*)(a1c + (size_t)v * 512 + d8) = *(uint4*)o;
}

// ---------------- layer1 aggregation, generic ----------------
__global__ __launch_bounds__(256) void k_agg1(const bf16* __restrict__ h1c,
                                              const int* __restrict__ rowptr,
                                              const int* __restrict__ csr_src,
                                              const float* __restrict__ dinv,
                                              const float* __restrict__ b1c, int c0, int C,
                                              bf16* __restrict__ a1c) {
    const int tshift = (C == 512) ? 7 : (C == 256) ? 6 : (C == 128) ? 5 : 4;
    long long gt = (long long)blockIdx.x * 256 + threadIdx.x;
    int v = (int)(gt >> tshift);
    int d4 = (int)((gt & ((1 << tshift) - 1)) << 2);
    if (v >= NNODES) return;
    float dv = dinv[v];
    uint2 w = *(const uint2*)(h1c + (size_t)v * C + d4);
    float s2 = dv * dv;
    float a0 = s2 * bfbits_lo(w.x), a1 = s2 * bfbits_hi(w.x);
    float a2 = s2 * bfbits_lo(w.y), a3 = s2 * bfbits_hi(w.y);
    int pend = rowptr[v + 1];
    for (int p = rowptr[v]; p < pend; ++p) {
        int u = csr_src[p];
        float nw = dinv[u] * dv;
        uint2 q = *(const uint2*)(h1c + (size_t)u * C + d4);
        a0 += nw * bfbits_lo(q.x); a1 += nw * bfbits_hi(q.x);
        a2 += nw * bfbits_lo(q.y); a3 += nw * bfbits_hi(q.y);
    }
    const float* bb = b1c + c0 + d4;
    a0 += bb[0]; a1 += bb[1]; a2 += bb[2]; a3 += bb[3];
    bf16 o[4];
    o[0] = __float2bfloat16(a0 > 0.f ? a0 : 0.f);
    o[1] = __float2bfloat16(a1 > 0.f ? a1 : 0.f);
    o[2] = __float2bfloat16(a2 > 0.f ? a2 : 0.f);
    o[3] = __float2bfloat16(a3 > 0.f ? a3 : 0.f);
    *(uint2*)(a1c + (size_t)v * C + d4) = *(uint2*)o;
}

// ---------------- GEMM2: 64-row x 64-col tiles, 128 threads / 2 waves ----------
// 782 blocks (3/CU, ~all-resident) instead of 391 heavyweight blocks. Same
// proven v3-style single-buffer 2-barrier loop. h2 padded to [N][64] for
// branchless full-width stores (W2T zero-pad -> pad cols compute to 0).
__global__ __launch_bounds__(128) void k_gemm2_64(
    const bf16* __restrict__ A, int C, const bf16* __restrict__ W2T, int kg0,
    float* __restrict__ h2, int accum) {
    __shared__ bf16 As[64 * 64];   // 8 KiB
    __shared__ bf16 Bs[64 * 64];   // 8 KiB
    const int tid = threadIdx.x;
    const int wave = tid >> 6, lane = tid & 63;
    const int row0 = blockIdx.x * 64;
    float4v acc[2][4];
#pragma unroll
    for (int i = 0; i < 2; i++)
#pragma unroll
        for (int j = 0; j < 4; j++) acc[i][j] = (float4v){0.f, 0.f, 0.f, 0.f};
    const int rb = wave * 32;
    const int frow = lane & 15;
    const int fk = lane >> 4;

    for (int kk = 0; kk < C; kk += 64) {
        __syncthreads();
#pragma unroll
        for (int t = 0; t < 4; ++t) {           // A: 64 rows
            int g8 = wave * 4 + t;
            int r = g8 * 8 + (lane >> 3);
            int gr = row0 + r; if (gr >= NNODES) gr = NNODES - 1;
            int ck = (lane & 7) ^ (r & 7);
            load_lds16(A + (size_t)gr * C + kk + ck * 8, &As[g8 * 8 * 64]);
        }
#pragma unroll
        for (int t = 0; t < 4; ++t) {           // B: 64 cols of W2T
            int g8 = wave * 4 + t;
            int cl = g8 * 8 + (lane >> 3);
            int ck = (lane & 7) ^ (cl & 7);
            load_lds16(W2T + (size_t)cl * HID + kg0 + kk + ck * 8, &Bs[g8 * 8 * 64]);
        }
        __syncthreads();
#pragma unroll
        for (int ki = 0; ki < 2; ++ki) {
            const int cc = ki * 4 + fk;
            short8 a[2], b8[4];
#pragma unroll
            for (int i = 0; i < 2; i++) {
                int r = rb + i * 16 + frow;
                a[i] = *(const short8*)&As[r * 64 + (cc ^ (r & 7)) * 8];
            }
#pragma unroll
            for (int j = 0; j < 4; j++) {
                int cl = j * 16 + frow;
                b8[j] = *(const short8*)&Bs[cl * 64 + (cc ^ (cl & 7)) * 8];
            }
#pragma unroll
            for (int i = 0; i < 2; i++)
#pragma unroll
                for (int j = 0; j < 4; j++)
                    acc[i][j] = __builtin_amdgcn_mfma_f32_16x16x32_bf16(a[i], b8[j], acc[i][j], 0, 0, 0);
        }
    }
#pragma unroll
    for (int i = 0; i < 2; i++) {
#pragma unroll
        for (int r = 0; r < 4; r++) {
            int grow = row0 + rb + i * 16 + (lane >> 4) * 4 + r;
            if (grow < NNODES) {
#pragma unroll
                for (int j = 0; j < 4; j++) {
                    size_t o = (size_t)grow * 64 + j * 16 + frow;
                    h2[o] = accum ? h2[o] + acc[i][j][r] : acc[i][j][r];
                }
            }
        }
    }
}

// ---------------- layer2 aggregation + bias -> out (h2 stride 64) -------------
__global__ __launch_bounds__(256) void k_agg2(const float* __restrict__ h2,
                                              const int* __restrict__ rowptr,
                                              const int* __restrict__ csr_src,
                                              const float* __restrict__ dinv,
                                              const float* __restrict__ b2c,
                                              void* out, const int* flags) {
    int v = blockIdx.x * 4 + (threadIdx.x >> 6);
    int d = threadIdx.x & 63;
    if (v >= NNODES || d >= NCLS) return;
    float dv = dinv[v];
    float acc = dv * dv * h2[(size_t)v * 64 + d];
    int pend = rowptr[v + 1];
    for (int p = rowptr[v]; p < pend; ++p) {
        int u = csr_src[p];
        acc += dinv[u] * dv * h2[(size_t)u * 64 + d];
    }
    acc += b2c[d];
    size_t o = (size_t)v * NCLS + d;
    if (flags[0]) ((bf16*)out)[o] = __float2bfloat16(acc);
    else          ((float*)out)[o] = acc;
}

extern "C" void kernel_launch(void* const* d_in, const int* in_sizes, int n_in,
                              void* d_out, int out_size, void* d_ws, size_t ws_size,
                              hipStream_t stream) {
    const void* x  = d_in[0];
    const void* ei = d_in[1];
    const void* W1 = d_in[2];
    const void* b1 = d_in[3];
    const void* W2 = d_in[4];
    const void* b2 = d_in[5];

    char* base = (char*)d_ws;
    auto alloc = [&](size_t bytes) -> char* {
        char* p = base;
        base += (bytes + 255) & ~(size_t)255;
        return p;
    };
    int*   flags  = (int*)alloc(64);
    int*   cnt    = (int*)alloc(sizeof(int) * NNODES);
    int*   part   = (int*)alloc(sizeof(int) * 256);
    int*   rowptr = (int*)alloc(sizeof(int) * (NNODES + 1));
    int*   cursor = (int*)alloc(sizeof(int) * NNODES);
    int*   csr    = (int*)alloc(sizeof(int) * NEDGES);
    float* dinv   = (float*)alloc(sizeof(float) * NNODES);
    bf16*  W1T    = (bf16*)alloc(sizeof(bf16) * DFEAT * HID);
    float* b1c    = (float*)alloc(sizeof(float) * HID);
    bf16*  W2T    = (bf16*)alloc(sizeof(bf16) * 64 * HID);
    float* b2c    = (float*)alloc(sizeof(float) * 64);
    float* h2     = (float*)alloc(sizeof(float) * (size_t)NNODES * 64);

    size_t used = (size_t)(base - (char*)d_ws);
    size_t rem = (ws_size > used) ? ws_size - used : 0;
    int C = 64;
    if (rem >= (size_t)200000 * 512 + 1024) C = 512;
    else if (rem >= (size_t)200000 * 256 + 1024) C = 256;
    else if (rem >= (size_t)200000 * 128 + 1024) C = 128;
    bf16* h1c = (bf16*)alloc(sizeof(bf16) * (size_t)NNODES * C);
    bf16* a1c = (bf16*)alloc(sizeof(bf16) * (size_t)NNODES * C);

    // fused prep: detect + zero(cnt) + all weight/bias conversions (1 launch)
    k_prep0<<<PR_GRID, 256, 0, stream>>>(x, ei, W1, b1, W2, b2, flags,
                                         (unsigned int*)cnt, W1T, b1c, W2T, b2c);
    k_count<<<(NEDGES + 255) / 256, 256, 0, stream>>>(ei, cnt, flags);
    const int nsb = (NNODES + 255) / 256;  // 196
    k_scan_part_dinv<<<nsb, 256, 0, stream>>>(cnt, part, dinv);
    k_scan_off<<<1, 256, 0, stream>>>(part, nsb);
    k_scan_fin<<<nsb, 256, 0, stream>>>(cnt, part, rowptr, cursor);
    k_fill<<<(NEDGES + 255) / 256, 256, 0, stream>>>(ei, cursor, csr, flags);

    const int rowblocks = (NNODES + 127) / 128;  // 391
    const int rows_per_xcd = (rowblocks + 7) / 8;  // 49
    int chunk_i = 0;
    for (int c0 = 0; c0 < HID; c0 += C, ++chunk_i) {
        if (C >= 128) {
            int col_tiles = C / 128;
            int nblk = 8 * rows_per_xcd * col_tiles;
            k_gemm1_v3<<<nblk, 256, 0, stream>>>(x, W1T, h1c, c0, C, flags,
                                                 col_tiles, rows_per_xcd, rowblocks);
        } else {
            dim3 g1(rowblocks, 1);
            k_gemm1_mfma<<<g1, 256, 0, stream>>>(x, W1T, h1c, c0, C, flags);
        }
        if (C == 512) {
            k_agg1_512<<<(NNODES + 3) / 4, 256, 0, stream>>>(h1c, rowptr, csr, dinv, b1c, a1c);
        } else {
            size_t nthr = (size_t)NNODES * (C / 4);
            k_agg1<<<(int)((nthr + 255) / 256), 256, 0, stream>>>(h1c, rowptr, csr, dinv, b1c, c0, C, a1c);
        }
        k_gemm2_64<<<(NNODES + 63) / 64, 128, 0, stream>>>(a1c, C, W2T, c0, h2, chunk_i > 0 ? 1 : 0);
    }

    k_agg2<<<(NNODES + 3) / 4, 256, 0, stream>>>(h2, rowptr, csr, dinv, b2c, d_out, flags);
}

// Round 6
// 321.450 us; speedup vs baseline: 1.3212x; 1.0458x over previous
//
#include <hip/hip_runtime.h>
#include <hip/hip_bf16.h>

#define NNODES 50000
#define NEDGES 150000
#define DFEAT  512
#define HID    512
#define NCLS   47

typedef __hip_bfloat16 bf16;
typedef __attribute__((ext_vector_type(8))) short short8;
typedef __attribute__((ext_vector_type(4))) float float4v;

typedef const __attribute__((address_space(1))) unsigned int* gas_t;
typedef __attribute__((address_space(3))) unsigned int* las_t;
__device__ __forceinline__ void load_lds16(const void* g, void* l) {
    __builtin_amdgcn_global_load_lds((gas_t)g, (las_t)l, 16, 0, 0);
}

__device__ __forceinline__ float bfbits_lo(unsigned int w) {
    return __uint_as_float((w & 0xFFFFu) << 16);
}
__device__ __forceinline__ float bfbits_hi(unsigned int w) {
    return __uint_as_float(w & 0xFFFF0000u);
}

__device__ __forceinline__ int eidx(const void* ei, int half, int e, int is64) {
    if (is64) return (int)((const long long*)ei)[(size_t)half * NEDGES + e];
    return ((const int*)ei)[half * NEDGES + e];
}

// ---------------- fused prep kernel: role-dispatched by blockIdx ----------------
// roles: [0] detect->flags | zero cnt | zero h2 (float4) | cvt W1T | cvt b1 |
//        cvt W2T | cvt b2.  cvt roles re-derive the bf16 flag locally.
#define ZB ((NNODES + 255) / 256)
#define NZH2 ((NNODES * 64 / 4 + 255) / 256)   // h2 zero: float4 per thread
#define PR_ZH2 (1 + ZB)
#define PR_W1T (PR_ZH2 + NZH2)
#define PR_B1  (PR_W1T + 1024)
#define PR_W2T (PR_B1 + 2)
#define PR_B2  (PR_W2T + 128)
#define PR_GRID (PR_B2 + 1)

__global__ __launch_bounds__(256) void k_prep0(
    const void* x, const void* ei, const void* W1, const void* b1,
    const void* W2, const void* b2, int* flags, unsigned int* cnt,
    bf16* W1T, float* b1c, bf16* W2T, float* b2c, float* h2) {
    __shared__ int sh[128];
    __shared__ int shflag;
    const int b = blockIdx.x, t = threadIdx.x;

    if (b >= 1 && b < 1 + ZB) {              // zero cnt
        int i = (b - 1) * 256 + t;
        if (i < NNODES) cnt[i] = 0u;
        return;
    }
    if (b >= PR_ZH2 && b < PR_W1T) {         // zero h2 (12.8 MB, float4/thread)
        int i = (b - PR_ZH2) * 256 + t;
        if (i < NNODES * 64 / 4)
            ((float4v*)h2)[i] = (float4v){0.f, 0.f, 0.f, 0.f};
        return;
    }

    // local bf16 detection (needed by all cvt roles; role 0 also writes flags)
    if (t < 64) {
        const unsigned short* xs = (const unsigned short*)x;
        int c = 0;
        for (int i = t; i < 256; i += 64) {
            unsigned int e = (xs[2 * i] >> 7) & 0xFF;
            c += (e >= 117 && e <= 130) ? 1 : 0;
        }
        sh[t] = c;
        if (b == 0) {
            const int* w = (const int*)ei;
            int o = 0;
            for (int i = 2 * t + 1; i < 512; i += 128) o |= w[i];
            sh[64 + t] = o;
        }
    }
    __syncthreads();
    if (t == 0) {
        int C = 0;
        for (int i = 0; i < 64; i++) C += sh[i];
        shflag = (C > 128) ? 1 : 0;
        if (b == 0) {
            int O = 0;
            for (int i = 0; i < 64; i++) O |= sh[64 + i];
            flags[0] = shflag;
            flags[1] = (O == 0) ? 1 : 0;
        }
    }
    __syncthreads();
    const int isb = shflag;

    if (b == 0) return;

    if (b >= PR_W1T && b < PR_B1) {          // W1 [K][N] -> W1T bf16 [N][K]
        int i = (b - PR_W1T) * 256 + t;
        int k = i / HID, n = i % HID;
        float v = isb ? __bfloat162float(((const bf16*)W1)[i]) : ((const float*)W1)[i];
        W1T[(size_t)n * DFEAT + k] = __float2bfloat16(v);
    } else if (b >= PR_B1 && b < PR_W2T) {   // b1 -> f32
        int i = (b - PR_B1) * 256 + t;
        if (i < HID)
            b1c[i] = isb ? __bfloat162float(((const bf16*)b1)[i]) : ((const float*)b1)[i];
    } else if (b >= PR_W2T && b < PR_B2) {   // W2 [K][47] -> W2T bf16 [64][512] pad
        int i = (b - PR_W2T) * 256 + t;
        int n = i / HID, k = i % HID;
        float v = 0.0f;
        if (n < NCLS) {
            size_t idx = (size_t)k * NCLS + n;
            v = isb ? __bfloat162float(((const bf16*)W2)[idx]) : ((const float*)W2)[idx];
        }
        W2T[(size_t)n * HID + k] = __float2bfloat16(v);
    } else if (b == PR_B2) {                 // b2 -> f32
        if (t < NCLS)
            b2c[t] = isb ? __bfloat162float(((const bf16*)b2)[t]) : ((const float*)b2)[t];
    }
}

// ---------------- graph structure ----------------
__global__ void k_count(const void* ei, int* cnt, const int* flags) {
    int e = blockIdx.x * blockDim.x + threadIdx.x;
    if (e >= NEDGES) return;
    atomicAdd(&cnt[eidx(ei, 1, e, flags[1])], 1);
}

__global__ __launch_bounds__(256) void k_scan_part_dinv(const int* cnt, int* part,
                                                        float* dinv) {
    __shared__ int s[256];
    int i = blockIdx.x * 256 + threadIdx.x;
    int v = (i < NNODES) ? cnt[i] : 0;
    if (i < NNODES) dinv[i] = rsqrtf(1.0f + (float)v);
    s[threadIdx.x] = v;
    __syncthreads();
    for (int off = 128; off > 0; off >>= 1) {
        if (threadIdx.x < off) s[threadIdx.x] += s[threadIdx.x + off];
        __syncthreads();
    }
    if (threadIdx.x == 0) part[blockIdx.x] = s[0];
}

__global__ __launch_bounds__(256) void k_scan_off(int* part, int n) {
    __shared__ int s[256];
    int v = (threadIdx.x < n) ? part[threadIdx.x] : 0;
    s[threadIdx.x] = v;
    __syncthreads();
    for (int off = 1; off < 256; off <<= 1) {
        int t = (threadIdx.x >= off) ? s[threadIdx.x - off] : 0;
        __syncthreads();
        s[threadIdx.x] += t;
        __syncthreads();
    }
    if (threadIdx.x < n) part[threadIdx.x] = s[threadIdx.x] - v;
}

__global__ __launch_bounds__(256) void k_scan_fin(const int* cnt, const int* part,
                                                  int* rowptr, int* cursor) {
    __shared__ int s[256];
    int i = blockIdx.x * 256 + threadIdx.x;
    int v = (i < NNODES) ? cnt[i] : 0;
    s[threadIdx.x] = v;
    __syncthreads();
    for (int off = 1; off < 256; off <<= 1) {
        int t = (threadIdx.x >= off) ? s[threadIdx.x - off] : 0;
        __syncthreads();
        s[threadIdx.x] += t;
        __syncthreads();
    }
    int incl = s[threadIdx.x] + part[blockIdx.x];
    if (i < NNODES) {
        rowptr[i + 1] = incl;
        cursor[i] = incl - v;
    }
    if (i == 0) rowptr[0] = 0;
}

__global__ void k_fill(const void* ei, int* cursor, int* csr_src, const int* flags) {
    int e = blockIdx.x * blockDim.x + threadIdx.x;
    if (e >= NEDGES) return;
    int is64 = flags[1];
    int v = eidx(ei, 1, e, is64);
    int u = eidx(ei, 0, e, is64);
    int pos = atomicAdd(&cursor[v], 1);
    csr_src[pos] = u;
}

// ---------------- aggx: ax = D^-1/2 (A+I) D^-1/2 X  (bf16 out) ----------------
// Reorder is exact: N·(X@W1) = (N·X)@W1 (N is linear row-mixing). One wave
// per node; f32-or-bf16 input handled per-flag (f32 aggregated in f32 before
// the single bf16 rounding -- better than the old per-element cast).
__global__ __launch_bounds__(256) void k_aggx(const void* __restrict__ X,
                                              const int* __restrict__ rowptr,
                                              const int* __restrict__ csr_src,
                                              const float* __restrict__ dinv,
                                              bf16* __restrict__ ax,
                                              const int* __restrict__ flags) {
    int v = blockIdx.x * 4 + (threadIdx.x >> 6);
    int lane = threadIdx.x & 63;
    if (v >= NNODES) return;
    int d8 = lane * 8;
    float dv = dinv[v];
    float s2 = dv * dv;
    float a0, a1, a2, a3, a4, a5, a6, a7;
    int pend = rowptr[v + 1];
    if (flags[0]) {
        const bf16* xb = (const bf16*)X;
        uint4 w = *(const uint4*)(xb + (size_t)v * 512 + d8);
        a0 = s2 * bfbits_lo(w.x); a1 = s2 * bfbits_hi(w.x);
        a2 = s2 * bfbits_lo(w.y); a3 = s2 * bfbits_hi(w.y);
        a4 = s2 * bfbits_lo(w.z); a5 = s2 * bfbits_hi(w.z);
        a6 = s2 * bfbits_lo(w.w); a7 = s2 * bfbits_hi(w.w);
        for (int p = rowptr[v]; p < pend; ++p) {
            int u = csr_src[p];
            float nw = dinv[u] * dv;
            uint4 q = *(const uint4*)(xb + (size_t)u * 512 + d8);
            a0 += nw * bfbits_lo(q.x); a1 += nw * bfbits_hi(q.x);
            a2 += nw * bfbits_lo(q.y); a3 += nw * bfbits_hi(q.y);
            a4 += nw * bfbits_lo(q.z); a5 += nw * bfbits_hi(q.z);
            a6 += nw * bfbits_lo(q.w); a7 += nw * bfbits_hi(q.w);
        }
    } else {
        const float* xf = (const float*)X;
        const float* p0 = xf + (size_t)v * 512 + d8;
        float4v f0 = *(const float4v*)p0, f1 = *(const float4v*)(p0 + 4);
        a0 = s2 * f0[0]; a1 = s2 * f0[1]; a2 = s2 * f0[2]; a3 = s2 * f0[3];
        a4 = s2 * f1[0]; a5 = s2 * f1[1]; a6 = s2 * f1[2]; a7 = s2 * f1[3];
        for (int p = rowptr[v]; p < pend; ++p) {
            int u = csr_src[p];
            float nw = dinv[u] * dv;
            const float* pu = xf + (size_t)u * 512 + d8;
            float4v g0 = *(const float4v*)pu, g1 = *(const float4v*)(pu + 4);
            a0 += nw * g0[0]; a1 += nw * g0[1]; a2 += nw * g0[2]; a3 += nw * g0[3];
            a4 += nw * g1[0]; a5 += nw * g1[1]; a6 += nw * g1[2]; a7 += nw * g1[3];
        }
    }
    bf16 o[8];
    o[0] = __float2bfloat16(a0); o[1] = __float2bfloat16(a1);
    o[2] = __float2bfloat16(a2); o[3] = __float2bfloat16(a3);
    o[4] = __float2bfloat16(a4); o[5] = __float2bfloat16(a5);
    o[6] = __float2bfloat16(a6); o[7] = __float2bfloat16(a7);
    *(uint4*)(ax + (size_t)v * 512 + d8) = *(uint4*)o;
}

// ---------------- fused GEMM: h2 += relu(ax@W1 + b1) @ W2  ----------------
// Phase 1 = round-0 v3 loop VERBATIM (128x128 tile, XOR-swizzled LDS, XCD
// remap), reading ax. Then bias+relu -> R staged into the SAME 32 KB LDS
// (acc1 dead after; disjoint acc2 lifetime keeps register peak at v3 level).
// Phase 2: R[128x128] @ W2T K-slice -> 128x64 partial, atomicAdd into h2
// (each cell receives exactly 4 adds, one per col-chunk block; h2 pre-zeroed
// in prep0). Eliminates h1c + a1c (150 MB traffic) and the gemm2 launch.
__global__ __launch_bounds__(256, 3) void k_fgemm(
    const bf16* __restrict__ ax, const bf16* __restrict__ W1T,
    const float* __restrict__ b1c, const bf16* __restrict__ W2T,
    float* __restrict__ h2, int rows_per_xcd, int n_row_tiles) {
    const int b = blockIdx.x;
    const int xcd = b & 7;
    const int s = b >> 3;
    const int col_t = s & 3;          // 4 col-chunks of 128
    const int lr = s >> 2;
    const int row_t = xcd * rows_per_xcd + lr;
    if (row_t >= n_row_tiles) return;

    __shared__ bf16 smem[128 * 128];  // 32 KiB: As|Bs in phase 1, R in phase 2
    bf16* As = smem;
    bf16* Bs = smem + 128 * 64;
    const int tid = threadIdx.x;
    const int wave = tid >> 6, lane = tid & 63;
    const int row0 = row_t * 128;
    const int gc0 = col_t * 128;

    const int rb = wave * 32;
    const int frow = lane & 15;
    const int fk = lane >> 4;

    float4v acc[2][8];
#pragma unroll
    for (int i = 0; i < 2; i++)
#pragma unroll
        for (int j = 0; j < 8; j++) acc[i][j] = (float4v){0.f, 0.f, 0.f, 0.f};

    // ---- phase 1: acc = ax_tile @ W1T[gc0..gc0+127] (v3 structure) ----
    for (int k0 = 0; k0 < DFEAT; k0 += 64) {
        __syncthreads();
#pragma unroll
        for (int t = 0; t < 4; ++t) {
            int g8 = wave * 4 + t;
            int r = g8 * 8 + (lane >> 3);
            int gr = row0 + r; if (gr >= NNODES) gr = NNODES - 1;
            int ck = (lane & 7) ^ (r & 7);
            load_lds16(ax + (size_t)gr * DFEAT + k0 + ck * 8, &As[g8 * 8 * 64]);
        }
#pragma unroll
        for (int t = 0; t < 4; ++t) {
            int g8 = wave * 4 + t;
            int cl = g8 * 8 + (lane >> 3);
            int ck = (lane & 7) ^ (cl & 7);
            load_lds16(W1T + (size_t)(gc0 + cl) * DFEAT + k0 + ck * 8, &Bs[g8 * 8 * 64]);
        }
        __syncthreads();
#pragma unroll
        for (int ki = 0; ki < 2; ++ki) {
            const int cc = ki * 4 + fk;
            short8 a[2], b8[8];
#pragma unroll
            for (int i = 0; i < 2; i++) {
                int r = rb + i * 16 + frow;
                a[i] = *(const short8*)&As[r * 64 + (cc ^ (r & 7)) * 8];
            }
#pragma unroll
            for (int j = 0; j < 8; j++) {
                int cl = j * 16 + frow;
                b8[j] = *(const short8*)&Bs[cl * 64 + (cc ^ (cl & 7)) * 8];
            }
#pragma unroll
            for (int i = 0; i < 2; i++)
#pragma unroll
                for (int j = 0; j < 8; j++)
                    acc[i][j] = __builtin_amdgcn_mfma_f32_16x16x32_bf16(a[i], b8[j], acc[i][j], 0, 0, 0);
        }
    }

    // ---- bias + relu -> R staged into smem [128 rows][128 cols], swizzled ----
    __syncthreads();   // all waves done reading As/Bs
    {
        float bias[8];
#pragma unroll
        for (int j = 0; j < 8; j++) bias[j] = b1c[gc0 + j * 16 + frow];
#pragma unroll
        for (int i = 0; i < 2; i++) {
#pragma unroll
            for (int r = 0; r < 4; r++) {
                int row = rb + i * 16 + fk * 4 + r;
#pragma unroll
                for (int j = 0; j < 8; j++) {
                    int col = j * 16 + frow;
                    float v = acc[i][j][r] + bias[j];
                    v = v > 0.f ? v : 0.f;
                    int ck2 = (col >> 3) ^ (row & 7);
                    smem[row * 128 + ck2 * 8 + (col & 7)] = __float2bfloat16(v);
                }
            }
        }
    }
    __syncthreads();

    // ---- phase 2: acc2 = R @ W2T[:, gc0..gc0+127]^T  (K=128, steps of 32) ----
    float4v acc2[2][4];
#pragma unroll
    for (int i = 0; i < 2; i++)
#pragma unroll
        for (int j = 0; j < 4; j++) acc2[i][j] = (float4v){0.f, 0.f, 0.f, 0.f};
#pragma unroll
    for (int ks = 0; ks < 4; ++ks) {
        const int kk = ks * 32 + fk * 8;          // k within the 128-chunk
        const int p = kk >> 3;                    // 16B chunk index
        short8 a2[2], b2f[4];
#pragma unroll
        for (int i = 0; i < 2; i++) {
            int row = rb + i * 16 + frow;
            a2[i] = *(const short8*)&smem[row * 128 + ((p ^ (row & 7)) * 8)];
        }
#pragma unroll
        for (int j = 0; j < 4; j++) {
            int n = j * 16 + frow;
            b2f[j] = *(const short8*)(W2T + (size_t)n * HID + gc0 + kk);
        }
#pragma unroll
        for (int i = 0; i < 2; i++)
#pragma unroll
            for (int j = 0; j < 4; j++)
                acc2[i][j] = __builtin_amdgcn_mfma_f32_16x16x32_bf16(a2[i], b2f[j], acc2[i][j], 0, 0, 0);
    }

    // ---- epilogue: atomic accumulate the K-slice partial into h2 ----
#pragma unroll
    for (int i = 0; i < 2; i++) {
#pragma unroll
        for (int r = 0; r < 4; r++) {
            int grow = row0 + rb + i * 16 + fk * 4 + r;
            if (grow < NNODES) {
#pragma unroll
                for (int j = 0; j < 4; j++)
                    atomicAdd(&h2[(size_t)grow * 64 + j * 16 + frow], acc2[i][j][r]);
            }
        }
    }
}

// ---------------- layer2 aggregation + bias -> out (h2 stride 64) -------------
__global__ __launch_bounds__(256) void k_agg2(const float* __restrict__ h2,
                                              const int* __restrict__ rowptr,
                                              const int* __restrict__ csr_src,
                                              const float* __restrict__ dinv,
                                              const float* __restrict__ b2c,
                                              void* out, const int* flags) {
    int v = blockIdx.x * 4 + (threadIdx.x >> 6);
    int d = threadIdx.x & 63;
    if (v >= NNODES || d >= NCLS) return;
    float dv = dinv[v];
    float acc = dv * dv * h2[(size_t)v * 64 + d];
    int pend = rowptr[v + 1];
    for (int p = rowptr[v]; p < pend; ++p) {
        int u = csr_src[p];
        acc += dinv[u] * dv * h2[(size_t)u * 64 + d];
    }
    acc += b2c[d];
    size_t o = (size_t)v * NCLS + d;
    if (flags[0]) ((bf16*)out)[o] = __float2bfloat16(acc);
    else          ((float*)out)[o] = acc;
}

extern "C" void kernel_launch(void* const* d_in, const int* in_sizes, int n_in,
                              void* d_out, int out_size, void* d_ws, size_t ws_size,
                              hipStream_t stream) {
    const void* x  = d_in[0];
    const void* ei = d_in[1];
    const void* W1 = d_in[2];
    const void* b1 = d_in[3];
    const void* W2 = d_in[4];
    const void* b2 = d_in[5];

    char* base = (char*)d_ws;
    auto alloc = [&](size_t bytes) -> char* {
        char* p = base;
        base += (bytes + 255) & ~(size_t)255;
        return p;
    };
    int*   flags  = (int*)alloc(64);
    int*   cnt    = (int*)alloc(sizeof(int) * NNODES);
    int*   part   = (int*)alloc(sizeof(int) * 256);
    int*   rowptr = (int*)alloc(sizeof(int) * (NNODES + 1));
    int*   cursor = (int*)alloc(sizeof(int) * NNODES);
    int*   csr    = (int*)alloc(sizeof(int) * NEDGES);
    float* dinv   = (float*)alloc(sizeof(float) * NNODES);
    bf16*  W1T    = (bf16*)alloc(sizeof(bf16) * DFEAT * HID);
    float* b1c    = (float*)alloc(sizeof(float) * HID);
    bf16*  W2T    = (bf16*)alloc(sizeof(bf16) * 64 * HID);
    float* b2c    = (float*)alloc(sizeof(float) * 64);
    float* h2     = (float*)alloc(sizeof(float) * (size_t)NNODES * 64);
    bf16*  ax     = (bf16*)alloc(sizeof(bf16) * (size_t)NNODES * DFEAT);

    // fused prep: detect + zero(cnt) + zero(h2) + all weight/bias conversions
    k_prep0<<<PR_GRID, 256, 0, stream>>>(x, ei, W1, b1, W2, b2, flags,
                                         (unsigned int*)cnt, W1T, b1c, W2T, b2c, h2);
    k_count<<<(NEDGES + 255) / 256, 256, 0, stream>>>(ei, cnt, flags);
    const int nsb = (NNODES + 255) / 256;  // 196
    k_scan_part_dinv<<<nsb, 256, 0, stream>>>(cnt, part, dinv);
    k_scan_off<<<1, 256, 0, stream>>>(part, nsb);
    k_scan_fin<<<nsb, 256, 0, stream>>>(cnt, part, rowptr, cursor);
    k_fill<<<(NEDGES + 255) / 256, 256, 0, stream>>>(ei, cursor, csr, flags);

    // ax = N·X  (reorder: N(XW1) == (NX)W1)
    k_aggx<<<(NNODES + 3) / 4, 256, 0, stream>>>(x, rowptr, csr, dinv, ax, flags);

    // fused: h2 += relu(ax@W1+b1) @ W2   (1568 blocks: 8 xcd x 49 x 4 chunks)
    const int rowblocks = (NNODES + 127) / 128;      // 391
    const int rows_per_xcd = (rowblocks + 7) / 8;    // 49
    k_fgemm<<<8 * rows_per_xcd * 4, 256, 0, stream>>>(ax, W1T, b1c, W2T, h2,
                                                      rows_per_xcd, rowblocks);

    k_agg2<<<(NNODES + 3) / 4, 256, 0, stream>>>(h2, rowptr, csr, dinv, b2c, d_out, flags);
}

// Round 7
// 319.314 us; speedup vs baseline: 1.3300x; 1.0067x over previous
//
#include <hip/hip_runtime.h>
#include <hip/hip_bf16.h>

#define NNODES 50000
#define NEDGES 150000
#define DFEAT  512
#define HID    512
#define NCLS   47

typedef __hip_bfloat16 bf16;
typedef __attribute__((ext_vector_type(8))) short short8;
typedef __attribute__((ext_vector_type(4))) float float4v;

typedef const __attribute__((address_space(1))) unsigned int* gas_t;
typedef __attribute__((address_space(3))) unsigned int* las_t;
__device__ __forceinline__ void load_lds16(const void* g, void* l) {
    __builtin_amdgcn_global_load_lds((gas_t)g, (las_t)l, 16, 0, 0);
}

__device__ __forceinline__ float bfbits_lo(unsigned int w) {
    return __uint_as_float((w & 0xFFFFu) << 16);
}
__device__ __forceinline__ float bfbits_hi(unsigned int w) {
    return __uint_as_float(w & 0xFFFF0000u);
}

__device__ __forceinline__ int eidx(const void* ei, int half, int e, int is64) {
    if (is64) return (int)((const long long*)ei)[(size_t)half * NEDGES + e];
    return ((const int*)ei)[half * NEDGES + e];
}

// ---------------- fused prep kernel: role-dispatched by blockIdx ----------------
#define ZB ((NNODES + 255) / 256)
#define NZH2 ((NNODES * 64 / 4 + 255) / 256)   // h2 zero: float4 per thread
#define PR_ZH2 (1 + ZB)
#define PR_W1T (PR_ZH2 + NZH2)
#define PR_B1  (PR_W1T + 1024)
#define PR_W2T (PR_B1 + 2)
#define PR_B2  (PR_W2T + 128)
#define PR_GRID (PR_B2 + 1)

__global__ __launch_bounds__(256) void k_prep0(
    const void* x, const void* ei, const void* W1, const void* b1,
    const void* W2, const void* b2, int* flags, unsigned int* cnt,
    bf16* W1T, float* b1c, bf16* W2T, float* b2c, float* h2) {
    __shared__ int sh[128];
    __shared__ int shflag;
    const int b = blockIdx.x, t = threadIdx.x;

    if (b >= 1 && b < 1 + ZB) {              // zero cnt
        int i = (b - 1) * 256 + t;
        if (i < NNODES) cnt[i] = 0u;
        return;
    }
    if (b >= PR_ZH2 && b < PR_W1T) {         // zero h2 (12.8 MB, float4/thread)
        int i = (b - PR_ZH2) * 256 + t;
        if (i < NNODES * 64 / 4)
            ((float4v*)h2)[i] = (float4v){0.f, 0.f, 0.f, 0.f};
        return;
    }

    // local bf16 detection (needed by all cvt roles; role 0 also writes flags)
    if (t < 64) {
        const unsigned short* xs = (const unsigned short*)x;
        int c = 0;
        for (int i = t; i < 256; i += 64) {
            unsigned int e = (xs[2 * i] >> 7) & 0xFF;
            c += (e >= 117 && e <= 130) ? 1 : 0;
        }
        sh[t] = c;
        if (b == 0) {
            const int* w = (const int*)ei;
            int o = 0;
            for (int i = 2 * t + 1; i < 512; i += 128) o |= w[i];
            sh[64 + t] = o;
        }
    }
    __syncthreads();
    if (t == 0) {
        int C = 0;
        for (int i = 0; i < 64; i++) C += sh[i];
        shflag = (C > 128) ? 1 : 0;
        if (b == 0) {
            int O = 0;
            for (int i = 0; i < 64; i++) O |= sh[64 + i];
            flags[0] = shflag;
            flags[1] = (O == 0) ? 1 : 0;
        }
    }
    __syncthreads();
    const int isb = shflag;

    if (b == 0) return;

    if (b >= PR_W1T && b < PR_B1) {          // W1 [K][N] -> W1T bf16 [N][K]
        int i = (b - PR_W1T) * 256 + t;
        int k = i / HID, n = i % HID;
        float v = isb ? __bfloat162float(((const bf16*)W1)[i]) : ((const float*)W1)[i];
        W1T[(size_t)n * DFEAT + k] = __float2bfloat16(v);
    } else if (b >= PR_B1 && b < PR_W2T) {   // b1 -> f32
        int i = (b - PR_B1) * 256 + t;
        if (i < HID)
            b1c[i] = isb ? __bfloat162float(((const bf16*)b1)[i]) : ((const float*)b1)[i];
    } else if (b >= PR_W2T && b < PR_B2) {   // W2 [K][47] -> W2T bf16 [64][512] pad
        int i = (b - PR_W2T) * 256 + t;
        int n = i / HID, k = i % HID;
        float v = 0.0f;
        if (n < NCLS) {
            size_t idx = (size_t)k * NCLS + n;
            v = isb ? __bfloat162float(((const bf16*)W2)[idx]) : ((const float*)W2)[idx];
        }
        W2T[(size_t)n * HID + k] = __float2bfloat16(v);
    } else if (b == PR_B2) {                 // b2 -> f32
        if (t < NCLS)
            b2c[t] = isb ? __bfloat162float(((const bf16*)b2)[t]) : ((const float*)b2)[t];
    }
}

// ---------------- graph structure ----------------
__global__ void k_count(const void* ei, int* cnt, const int* flags) {
    int e = blockIdx.x * blockDim.x + threadIdx.x;
    if (e >= NEDGES) return;
    atomicAdd(&cnt[eidx(ei, 1, e, flags[1])], 1);
}

__global__ __launch_bounds__(256) void k_scan_part_dinv(const int* cnt, int* part,
                                                        float* dinv) {
    __shared__ int s[256];
    int i = blockIdx.x * 256 + threadIdx.x;
    int v = (i < NNODES) ? cnt[i] : 0;
    if (i < NNODES) dinv[i] = rsqrtf(1.0f + (float)v);
    s[threadIdx.x] = v;
    __syncthreads();
    for (int off = 128; off > 0; off >>= 1) {
        if (threadIdx.x < off) s[threadIdx.x] += s[threadIdx.x + off];
        __syncthreads();
    }
    if (threadIdx.x == 0) part[blockIdx.x] = s[0];
}

__global__ __launch_bounds__(256) void k_scan_off(int* part, int n) {
    __shared__ int s[256];
    int v = (threadIdx.x < n) ? part[threadIdx.x] : 0;
    s[threadIdx.x] = v;
    __syncthreads();
    for (int off = 1; off < 256; off <<= 1) {
        int t = (threadIdx.x >= off) ? s[threadIdx.x - off] : 0;
        __syncthreads();
        s[threadIdx.x] += t;
        __syncthreads();
    }
    if (threadIdx.x < n) part[threadIdx.x] = s[threadIdx.x] - v;
}

__global__ __launch_bounds__(256) void k_scan_fin(const int* cnt, const int* part,
                                                  int* rowptr, int* cursor) {
    __shared__ int s[256];
    int i = blockIdx.x * 256 + threadIdx.x;
    int v = (i < NNODES) ? cnt[i] : 0;
    s[threadIdx.x] = v;
    __syncthreads();
    for (int off = 1; off < 256; off <<= 1) {
        int t = (threadIdx.x >= off) ? s[threadIdx.x - off] : 0;
        __syncthreads();
        s[threadIdx.x] += t;
        __syncthreads();
    }
    int incl = s[threadIdx.x] + part[blockIdx.x];
    if (i < NNODES) {
        rowptr[i + 1] = incl;
        cursor[i] = incl - v;
    }
    if (i == 0) rowptr[0] = 0;
}

__global__ void k_fill(const void* ei, int* cursor, int* csr_src, const int* flags) {
    int e = blockIdx.x * blockDim.x + threadIdx.x;
    if (e >= NEDGES) return;
    int is64 = flags[1];
    int v = eidx(ei, 1, e, is64);
    int u = eidx(ei, 0, e, is64);
    int pos = atomicAdd(&cursor[v], 1);
    csr_src[pos] = u;
}

// ---------------- aggx: ax = D^-1/2 (A+I) D^-1/2 X  (bf16 out) ----------------
// Latency fix (R6 counters: 3.3 TB/s, all pipes idle -> serial gather chain):
// masked chunk-4 neighbor loop. Every chunk issues 4 index + 4 dinv + 4 row
// loads unconditionally; out-of-range slots clamp to the chunk's first edge
// with weight 0 (dup row-load = L1 hit). Serial depth/node: ~3 -> ~1.2.
__global__ __launch_bounds__(256) void k_aggx(const void* __restrict__ X,
                                              const int* __restrict__ rowptr,
                                              const int* __restrict__ csr_src,
                                              const float* __restrict__ dinv,
                                              bf16* __restrict__ ax,
                                              const int* __restrict__ flags) {
    int v = blockIdx.x * 4 + (threadIdx.x >> 6);
    int lane = threadIdx.x & 63;
    if (v >= NNODES) return;
    int d8 = lane * 8;
    float dv = dinv[v];
    float s2 = dv * dv;
    float a0, a1, a2, a3, a4, a5, a6, a7;
    int pend = rowptr[v + 1];
    if (flags[0]) {
        const bf16* xb = (const bf16*)X;
        uint4 w = *(const uint4*)(xb + (size_t)v * 512 + d8);
        a0 = s2 * bfbits_lo(w.x); a1 = s2 * bfbits_hi(w.x);
        a2 = s2 * bfbits_lo(w.y); a3 = s2 * bfbits_hi(w.y);
        a4 = s2 * bfbits_lo(w.z); a5 = s2 * bfbits_hi(w.z);
        a6 = s2 * bfbits_lo(w.w); a7 = s2 * bfbits_hi(w.w);
        for (int p = rowptr[v]; p < pend; p += 4) {
            int j1 = (p + 1 < pend) ? p + 1 : p;
            int j2 = (p + 2 < pend) ? p + 2 : p;
            int j3 = (p + 3 < pend) ? p + 3 : p;
            int u0 = csr_src[p], u1 = csr_src[j1];
            int u2 = csr_src[j2], u3 = csr_src[j3];
            float nw0 = dinv[u0] * dv;
            float nw1 = (p + 1 < pend) ? dinv[u1] * dv : 0.f;
            float nw2 = (p + 2 < pend) ? dinv[u2] * dv : 0.f;
            float nw3 = (p + 3 < pend) ? dinv[u3] * dv : 0.f;
            uint4 q0 = *(const uint4*)(xb + (size_t)u0 * 512 + d8);
            uint4 q1 = *(const uint4*)(xb + (size_t)u1 * 512 + d8);
            uint4 q2 = *(const uint4*)(xb + (size_t)u2 * 512 + d8);
            uint4 q3 = *(const uint4*)(xb + (size_t)u3 * 512 + d8);
            a0 += nw0 * bfbits_lo(q0.x) + nw1 * bfbits_lo(q1.x)
                + nw2 * bfbits_lo(q2.x) + nw3 * bfbits_lo(q3.x);
            a1 += nw0 * bfbits_hi(q0.x) + nw1 * bfbits_hi(q1.x)
                + nw2 * bfbits_hi(q2.x) + nw3 * bfbits_hi(q3.x);
            a2 += nw0 * bfbits_lo(q0.y) + nw1 * bfbits_lo(q1.y)
                + nw2 * bfbits_lo(q2.y) + nw3 * bfbits_lo(q3.y);
            a3 += nw0 * bfbits_hi(q0.y) + nw1 * bfbits_hi(q1.y)
                + nw2 * bfbits_hi(q2.y) + nw3 * bfbits_hi(q3.y);
            a4 += nw0 * bfbits_lo(q0.z) + nw1 * bfbits_lo(q1.z)
                + nw2 * bfbits_lo(q2.z) + nw3 * bfbits_lo(q3.z);
            a5 += nw0 * bfbits_hi(q0.z) + nw1 * bfbits_hi(q1.z)
                + nw2 * bfbits_hi(q2.z) + nw3 * bfbits_hi(q3.z);
            a6 += nw0 * bfbits_lo(q0.w) + nw1 * bfbits_lo(q1.w)
                + nw2 * bfbits_lo(q2.w) + nw3 * bfbits_lo(q3.w);
            a7 += nw0 * bfbits_hi(q0.w) + nw1 * bfbits_hi(q1.w)
                + nw2 * bfbits_hi(q2.w) + nw3 * bfbits_hi(q3.w);
        }
    } else {
        const float* xf = (const float*)X;
        const float* p0 = xf + (size_t)v * 512 + d8;
        float4v f0 = *(const float4v*)p0, f1 = *(const float4v*)(p0 + 4);
        a0 = s2 * f0[0]; a1 = s2 * f0[1]; a2 = s2 * f0[2]; a3 = s2 * f0[3];
        a4 = s2 * f1[0]; a5 = s2 * f1[1]; a6 = s2 * f1[2]; a7 = s2 * f1[3];
        for (int p = rowptr[v]; p < pend; ++p) {
            int u = csr_src[p];
            float nw = dinv[u] * dv;
            const float* pu = xf + (size_t)u * 512 + d8;
            float4v g0 = *(const float4v*)pu, g1 = *(const float4v*)(pu + 4);
            a0 += nw * g0[0]; a1 += nw * g0[1]; a2 += nw * g0[2]; a3 += nw * g0[3];
            a4 += nw * g1[0]; a5 += nw * g1[1]; a6 += nw * g1[2]; a7 += nw * g1[3];
        }
    }
    bf16 o[8];
    o[0] = __float2bfloat16(a0); o[1] = __float2bfloat16(a1);
    o[2] = __float2bfloat16(a2); o[3] = __float2bfloat16(a3);
    o[4] = __float2bfloat16(a4); o[5] = __float2bfloat16(a5);
    o[6] = __float2bfloat16(a6); o[7] = __float2bfloat16(a7);
    *(uint4*)(ax + (size_t)v * 512 + d8) = *(uint4*)o;
}

// ---------------- fused GEMM: h2 += relu(ax@W1 + b1) @ W2  ----------------
__global__ __launch_bounds__(256, 3) void k_fgemm(
    const bf16* __restrict__ ax, const bf16* __restrict__ W1T,
    const float* __restrict__ b1c, const bf16* __restrict__ W2T,
    float* __restrict__ h2, int rows_per_xcd, int n_row_tiles) {
    const int b = blockIdx.x;
    const int xcd = b & 7;
    const int s = b >> 3;
    const int col_t = s & 3;          // 4 col-chunks of 128
    const int lr = s >> 2;
    const int row_t = xcd * rows_per_xcd + lr;
    if (row_t >= n_row_tiles) return;

    __shared__ bf16 smem[128 * 128];  // 32 KiB: As|Bs in phase 1, R in phase 2
    bf16* As = smem;
    bf16* Bs = smem + 128 * 64;
    const int tid = threadIdx.x;
    const int wave = tid >> 6, lane = tid & 63;
    const int row0 = row_t * 128;
    const int gc0 = col_t * 128;

    const int rb = wave * 32;
    const int frow = lane & 15;
    const int fk = lane >> 4;

    float4v acc[2][8];
#pragma unroll
    for (int i = 0; i < 2; i++)
#pragma unroll
        for (int j = 0; j < 8; j++) acc[i][j] = (float4v){0.f, 0.f, 0.f, 0.f};

    // ---- phase 1: acc = ax_tile @ W1T[gc0..gc0+127] (v3 structure) ----
    for (int k0 = 0; k0 < DFEAT; k0 += 64) {
        __syncthreads();
#pragma unroll
        for (int t = 0; t < 4; ++t) {
            int g8 = wave * 4 + t;
            int r = g8 * 8 + (lane >> 3);
            int gr = row0 + r; if (gr >= NNODES) gr = NNODES - 1;
            int ck = (lane & 7) ^ (r & 7);
            load_lds16(ax + (size_t)gr * DFEAT + k0 + ck * 8, &As[g8 * 8 * 64]);
        }
#pragma unroll
        for (int t = 0; t < 4; ++t) {
            int g8 = wave * 4 + t;
            int cl = g8 * 8 + (lane >> 3);
            int ck = (lane & 7) ^ (cl & 7);
            load_lds16(W1T + (size_t)(gc0 + cl) * DFEAT + k0 + ck * 8, &Bs[g8 * 8 * 64]);
        }
        __syncthreads();
#pragma unroll
        for (int ki = 0; ki < 2; ++ki) {
            const int cc = ki * 4 + fk;
            short8 a[2], b8[8];
#pragma unroll
            for (int i = 0; i < 2; i++) {
                int r = rb + i * 16 + frow;
                a[i] = *(const short8*)&As[r * 64 + (cc ^ (r & 7)) * 8];
            }
#pragma unroll
            for (int j = 0; j < 8; j++) {
                int cl = j * 16 + frow;
                b8[j] = *(const short8*)&Bs[cl * 64 + (cc ^ (cl & 7)) * 8];
            }
#pragma unroll
            for (int i = 0; i < 2; i++)
#pragma unroll
                for (int j = 0; j < 8; j++)
                    acc[i][j] = __builtin_amdgcn_mfma_f32_16x16x32_bf16(a[i], b8[j], acc[i][j], 0, 0, 0);
        }
    }

    // ---- bias + relu -> R staged into smem [128 rows][128 cols], swizzled ----
    __syncthreads();   // all waves done reading As/Bs
    {
        float bias[8];
#pragma unroll
        for (int j = 0; j < 8; j++) bias[j] = b1c[gc0 + j * 16 + frow];
#pragma unroll
        for (int i = 0; i < 2; i++) {
#pragma unroll
            for (int r = 0; r < 4; r++) {
                int row = rb + i * 16 + fk * 4 + r;
#pragma unroll
                for (int j = 0; j < 8; j++) {
                    int col = j * 16 + frow;
                    float v = acc[i][j][r] + bias[j];
                    v = v > 0.f ? v : 0.f;
                    int ck2 = (col >> 3) ^ (row & 7);
                    smem[row * 128 + ck2 * 8 + (col & 7)] = __float2bfloat16(v);
                }
            }
        }
    }
    __syncthreads();

    // ---- phase 2: acc2 = R @ W2T[:, gc0..gc0+127]^T  (K=128, steps of 32) ----
    float4v acc2[2][4];
#pragma unroll
    for (int i = 0; i < 2; i++)
#pragma unroll
        for (int j = 0; j < 4; j++) acc2[i][j] = (float4v){0.f, 0.f, 0.f, 0.f};
#pragma unroll
    for (int ks = 0; ks < 4; ++ks) {
        const int kk = ks * 32 + fk * 8;          // k within the 128-chunk
        const int p = kk >> 3;                    // 16B chunk index
        short8 a2[2], b2f[4];
#pragma unroll
        for (int i = 0; i < 2; i++) {
            int row = rb + i * 16 + frow;
            a2[i] = *(const short8*)&smem[row * 128 + ((p ^ (row & 7)) * 8)];
        }
#pragma unroll
        for (int j = 0; j < 4; j++) {
            int n = j * 16 + frow;
            b2f[j] = *(const short8*)(W2T + (size_t)n * HID + gc0 + kk);
        }
#pragma unroll
        for (int i = 0; i < 2; i++)
#pragma unroll
            for (int j = 0; j < 4; j++)
                acc2[i][j] = __builtin_amdgcn_mfma_f32_16x16x32_bf16(a2[i], b2f[j], acc2[i][j], 0, 0, 0);
    }

    // ---- epilogue: atomic accumulate the K-slice partial into h2 ----
#pragma unroll
    for (int i = 0; i < 2; i++) {
#pragma unroll
        for (int r = 0; r < 4; r++) {
            int grow = row0 + rb + i * 16 + fk * 4 + r;
            if (grow < NNODES) {
#pragma unroll
                for (int j = 0; j < 4; j++)
                    atomicAdd(&h2[(size_t)grow * 64 + j * 16 + frow], acc2[i][j][r]);
            }
        }
    }
}

// ---------------- layer2 aggregation + bias -> out (h2 stride 64) -------------
// Same masked chunk-4 gather fix as aggx.
__global__ __launch_bounds__(256) void k_agg2(const float* __restrict__ h2,
                                              const int* __restrict__ rowptr,
                                              const int* __restrict__ csr_src,
                                              const float* __restrict__ dinv,
                                              const float* __restrict__ b2c,
                                              void* out, const int* flags) {
    int v = blockIdx.x * 4 + (threadIdx.x >> 6);
    int d = threadIdx.x & 63;
    if (v >= NNODES || d >= NCLS) return;
    float dv = dinv[v];
    float acc = dv * dv * h2[(size_t)v * 64 + d];
    int pend = rowptr[v + 1];
    for (int p = rowptr[v]; p < pend; p += 4) {
        int j1 = (p + 1 < pend) ? p + 1 : p;
        int j2 = (p + 2 < pend) ? p + 2 : p;
        int j3 = (p + 3 < pend) ? p + 3 : p;
        int u0 = csr_src[p], u1 = csr_src[j1];
        int u2 = csr_src[j2], u3 = csr_src[j3];
        float nw0 = dinv[u0] * dv;
        float nw1 = (p + 1 < pend) ? dinv[u1] * dv : 0.f;
        float nw2 = (p + 2 < pend) ? dinv[u2] * dv : 0.f;
        float nw3 = (p + 3 < pend) ? dinv[u3] * dv : 0.f;
        float q0 = h2[(size_t)u0 * 64 + d];
        float q1 = h2[(size_t)u1 * 64 + d];
        float q2 = h2[(size_t)u2 * 64 + d];
        float q3 = h2[(size_t)u3 * 64 + d];
        acc += nw0 * q0 + nw1 * q1 + nw2 * q2 + nw3 * q3;
    }
    acc += b2c[d];
    size_t o = (size_t)v * NCLS + d;
    if (flags[0]) ((bf16*)out)[o] = __float2bfloat16(acc);
    else          ((float*)out)[o] = acc;
}

extern "C" void kernel_launch(void* const* d_in, const int* in_sizes, int n_in,
                              void* d_out, int out_size, void* d_ws, size_t ws_size,
                              hipStream_t stream) {
    const void* x  = d_in[0];
    const void* ei = d_in[1];
    const void* W1 = d_in[2];
    const void* b1 = d_in[3];
    const void* W2 = d_in[4];
    const void* b2 = d_in[5];

    char* base = (char*)d_ws;
    auto alloc = [&](size_t bytes) -> char* {
        char* p = base;
        base += (bytes + 255) & ~(size_t)255;
        return p;
    };
    int*   flags  = (int*)alloc(64);
    int*   cnt    = (int*)alloc(sizeof(int) * NNODES);
    int*   part   = (int*)alloc(sizeof(int) * 256);
    int*   rowptr = (int*)alloc(sizeof(int) * (NNODES + 1));
    int*   cursor = (int*)alloc(sizeof(int) * NNODES);
    int*   csr    = (int*)alloc(sizeof(int) * NEDGES);
    float* dinv   = (float*)alloc(sizeof(float) * NNODES);
    bf16*  W1T    = (bf16*)alloc(sizeof(bf16) * DFEAT * HID);
    float* b1c    = (float*)alloc(sizeof(float) * HID);
    bf16*  W2T    = (bf16*)alloc(sizeof(bf16) * 64 * HID);
    float* b2c    = (float*)alloc(sizeof(float) * 64);
    float* h2     = (float*)alloc(sizeof(float) * (size_t)NNODES * 64);
    bf16*  ax     = (bf16*)alloc(sizeof(bf16) * (size_t)NNODES * DFEAT);

    // fused prep: detect + zero(cnt) + zero(h2) + all weight/bias conversions
    k_prep0<<<PR_GRID, 256, 0, stream>>>(x, ei, W1, b1, W2, b2, flags,
                                         (unsigned int*)cnt, W1T, b1c, W2T, b2c, h2);
    k_count<<<(NEDGES + 255) / 256, 256, 0, stream>>>(ei, cnt, flags);
    const int nsb = (NNODES + 255) / 256;  // 196
    k_scan_part_dinv<<<nsb, 256, 0, stream>>>(cnt, part, dinv);
    k_scan_off<<<1, 256, 0, stream>>>(part, nsb);
    k_scan_fin<<<nsb, 256, 0, stream>>>(cnt, part, rowptr, cursor);
    k_fill<<<(NEDGES + 255) / 256, 256, 0, stream>>>(ei, cursor, csr, flags);

    // ax = N·X  (reorder: N(XW1) == (NX)W1)
    k_aggx<<<(NNODES + 3) / 4, 256, 0, stream>>>(x, rowptr, csr, dinv, ax, flags);

    // fused: h2 += relu(ax@W1+b1) @ W2   (1568 blocks: 8 xcd x 49 x 4 chunks)
    const int rowblocks = (NNODES + 127) / 128;      // 391
    const int rows_per_xcd = (rowblocks + 7) / 8;    // 49
    k_fgemm<<<8 * rows_per_xcd * 4, 256, 0, stream>>>(ax, W1T, b1c, W2T, h2,
                                                      rows_per_xcd, rowblocks);

    k_agg2<<<(NNODES + 3) / 4, 256, 0, stream>>>(h2, rowptr, csr, dinv, b2c, d_out, flags);
}

// Round 8
// 315.877 us; speedup vs baseline: 1.3445x; 1.0109x over previous
//
#include <hip/hip_runtime.h>
#include <hip/hip_bf16.h>

#define NNODES 50000
#define NEDGES 150000
#define DFEAT  512
#define HID    512
#define NCLS   47

typedef __hip_bfloat16 bf16;
typedef __attribute__((ext_vector_type(8))) short short8;
typedef __attribute__((ext_vector_type(4))) float float4v;

typedef const __attribute__((address_space(1))) unsigned int* gas_t;
typedef __attribute__((address_space(3))) unsigned int* las_t;
__device__ __forceinline__ void load_lds16(const void* g, void* l) {
    __builtin_amdgcn_global_load_lds((gas_t)g, (las_t)l, 16, 0, 0);
}

__device__ __forceinline__ float bfbits_lo(unsigned int w) {
    return __uint_as_float((w & 0xFFFFu) << 16);
}
__device__ __forceinline__ float bfbits_hi(unsigned int w) {
    return __uint_as_float(w & 0xFFFF0000u);
}

__device__ __forceinline__ int eidx(const void* ei, int half, int e, int is64) {
    if (is64) return (int)((const long long*)ei)[(size_t)half * NEDGES + e];
    return ((const int*)ei)[half * NEDGES + e];
}

// ---------------- fused prep kernel: role-dispatched by blockIdx ----------------
#define ZB ((NNODES + 255) / 256)
#define NZH2 ((NNODES * 64 / 4 + 255) / 256)   // h2 zero: float4 per thread
#define PR_ZH2 (1 + ZB)
#define PR_W1T (PR_ZH2 + NZH2)
#define PR_B1  (PR_W1T + 1024)
#define PR_W2T (PR_B1 + 2)
#define PR_B2  (PR_W2T + 128)
#define PR_GRID (PR_B2 + 1)

__global__ __launch_bounds__(256) void k_prep0(
    const void* x, const void* ei, const void* W1, const void* b1,
    const void* W2, const void* b2, int* flags, unsigned int* cnt,
    bf16* W1T, float* b1c, bf16* W2T, float* b2c, float* h2) {
    __shared__ int sh[128];
    __shared__ int shflag;
    const int b = blockIdx.x, t = threadIdx.x;

    if (b >= 1 && b < 1 + ZB) {              // zero cnt
        int i = (b - 1) * 256 + t;
        if (i < NNODES) cnt[i] = 0u;
        return;
    }
    if (b >= PR_ZH2 && b < PR_W1T) {         // zero h2 (12.8 MB, float4/thread)
        int i = (b - PR_ZH2) * 256 + t;
        if (i < NNODES * 64 / 4)
            ((float4v*)h2)[i] = (float4v){0.f, 0.f, 0.f, 0.f};
        return;
    }

    // local bf16 detection (needed by all cvt roles; role 0 also writes flags)
    if (t < 64) {
        const unsigned short* xs = (const unsigned short*)x;
        int c = 0;
        for (int i = t; i < 256; i += 64) {
            unsigned int e = (xs[2 * i] >> 7) & 0xFF;
            c += (e >= 117 && e <= 130) ? 1 : 0;
        }
        sh[t] = c;
        if (b == 0) {
            const int* w = (const int*)ei;
            int o = 0;
            for (int i = 2 * t + 1; i < 512; i += 128) o |= w[i];
            sh[64 + t] = o;
        }
    }
    __syncthreads();
    if (t == 0) {
        int C = 0;
        for (int i = 0; i < 64; i++) C += sh[i];
        shflag = (C > 128) ? 1 : 0;
        if (b == 0) {
            int O = 0;
            for (int i = 0; i < 64; i++) O |= sh[64 + i];
            flags[0] = shflag;
            flags[1] = (O == 0) ? 1 : 0;
        }
    }
    __syncthreads();
    const int isb = shflag;

    if (b == 0) return;

    if (b >= PR_W1T && b < PR_B1) {          // W1 [K][N] -> W1T bf16 [N][K]
        int i = (b - PR_W1T) * 256 + t;
        int k = i / HID, n = i % HID;
        float v = isb ? __bfloat162float(((const bf16*)W1)[i]) : ((const float*)W1)[i];
        W1T[(size_t)n * DFEAT + k] = __float2bfloat16(v);
    } else if (b >= PR_B1 && b < PR_W2T) {   // b1 -> f32
        int i = (b - PR_B1) * 256 + t;
        if (i < HID)
            b1c[i] = isb ? __bfloat162float(((const bf16*)b1)[i]) : ((const float*)b1)[i];
    } else if (b >= PR_W2T && b < PR_B2) {   // W2 [K][47] -> W2T bf16 [64][512] pad
        int i = (b - PR_W2T) * 256 + t;
        int n = i / HID, k = i % HID;
        float v = 0.0f;
        if (n < NCLS) {
            size_t idx = (size_t)k * NCLS + n;
            v = isb ? __bfloat162float(((const bf16*)W2)[idx]) : ((const float*)W2)[idx];
        }
        W2T[(size_t)n * HID + k] = __float2bfloat16(v);
    } else if (b == PR_B2) {                 // b2 -> f32
        if (t < NCLS)
            b2c[t] = isb ? __bfloat162float(((const bf16*)b2)[t]) : ((const float*)b2)[t];
    }
}

// ---------------- graph structure ----------------
__global__ void k_count(const void* ei, int* cnt, const int* flags) {
    int e = blockIdx.x * blockDim.x + threadIdx.x;
    if (e >= NEDGES) return;
    atomicAdd(&cnt[eidx(ei, 1, e, flags[1])], 1);
}

__global__ __launch_bounds__(256) void k_scan_part_dinv(const int* cnt, int* part,
                                                        float* dinv) {
    __shared__ int s[256];
    int i = blockIdx.x * 256 + threadIdx.x;
    int v = (i < NNODES) ? cnt[i] : 0;
    if (i < NNODES) dinv[i] = rsqrtf(1.0f + (float)v);
    s[threadIdx.x] = v;
    __syncthreads();
    for (int off = 128; off > 0; off >>= 1) {
        if (threadIdx.x < off) s[threadIdx.x] += s[threadIdx.x + off];
        __syncthreads();
    }
    if (threadIdx.x == 0) part[blockIdx.x] = s[0];
}

__global__ __launch_bounds__(256) void k_scan_off(int* part, int n) {
    __shared__ int s[256];
    int v = (threadIdx.x < n) ? part[threadIdx.x] : 0;
    s[threadIdx.x] = v;
    __syncthreads();
    for (int off = 1; off < 256; off <<= 1) {
        int t = (threadIdx.x >= off) ? s[threadIdx.x - off] : 0;
        __syncthreads();
        s[threadIdx.x] += t;
        __syncthreads();
    }
    if (threadIdx.x < n) part[threadIdx.x] = s[threadIdx.x] - v;
}

__global__ __launch_bounds__(256) void k_scan_fin(const int* cnt, const int* part,
                                                  int* rowptr, int* cursor) {
    __shared__ int s[256];
    int i = blockIdx.x * 256 + threadIdx.x;
    int v = (i < NNODES) ? cnt[i] : 0;
    s[threadIdx.x] = v;
    __syncthreads();
    for (int off = 1; off < 256; off <<= 1) {
        int t = (threadIdx.x >= off) ? s[threadIdx.x - off] : 0;
        __syncthreads();
        s[threadIdx.x] += t;
        __syncthreads();
    }
    int incl = s[threadIdx.x] + part[blockIdx.x];
    if (i < NNODES) {
        rowptr[i + 1] = incl;
        cursor[i] = incl - v;
    }
    if (i == 0) rowptr[0] = 0;
}

__global__ void k_fill(const void* ei, int* cursor, int* csr_src, const int* flags) {
    int e = blockIdx.x * blockDim.x + threadIdx.x;
    if (e >= NEDGES) return;
    int is64 = flags[1];
    int v = eidx(ei, 1, e, is64);
    int u = eidx(ei, 0, e, is64);
    int pos = atomicAdd(&cursor[v], 1);
    csr_src[pos] = u;
}

// ---------------- aggx: ax = D^-1/2 (A+I) D^-1/2 X  (bf16 out) ----------------
// Masked chunk-8 gather: Poisson(3) degrees -> 98% of nodes resolve in ONE
// chunk (was 1-2 at chunk-4). Out-of-range slots clamp to the chunk's first
// edge with weight 0 (dup loads = L1 hits).
__global__ __launch_bounds__(256) void k_aggx(const void* __restrict__ X,
                                              const int* __restrict__ rowptr,
                                              const int* __restrict__ csr_src,
                                              const float* __restrict__ dinv,
                                              bf16* __restrict__ ax,
                                              const int* __restrict__ flags) {
    int v = blockIdx.x * 4 + (threadIdx.x >> 6);
    int lane = threadIdx.x & 63;
    if (v >= NNODES) return;
    int d8 = lane * 8;
    float dv = dinv[v];
    float s2 = dv * dv;
    float a0, a1, a2, a3, a4, a5, a6, a7;
    int pend = rowptr[v + 1];
    if (flags[0]) {
        const bf16* xb = (const bf16*)X;
        uint4 w = *(const uint4*)(xb + (size_t)v * 512 + d8);
        a0 = s2 * bfbits_lo(w.x); a1 = s2 * bfbits_hi(w.x);
        a2 = s2 * bfbits_lo(w.y); a3 = s2 * bfbits_hi(w.y);
        a4 = s2 * bfbits_lo(w.z); a5 = s2 * bfbits_hi(w.z);
        a6 = s2 * bfbits_lo(w.w); a7 = s2 * bfbits_hi(w.w);
        for (int p = rowptr[v]; p < pend; p += 8) {
            int u[8]; float nw[8];
#pragma unroll
            for (int c = 0; c < 8; ++c) {
                int jp = (p + c < pend) ? p + c : p;
                u[c] = csr_src[jp];
            }
#pragma unroll
            for (int c = 0; c < 8; ++c)
                nw[c] = (p + c < pend) ? dinv[u[c]] * dv : 0.f;
#pragma unroll
            for (int c = 0; c < 8; ++c) {
                uint4 q = *(const uint4*)(xb + (size_t)u[c] * 512 + d8);
                float nwc = nw[c];
                a0 += nwc * bfbits_lo(q.x); a1 += nwc * bfbits_hi(q.x);
                a2 += nwc * bfbits_lo(q.y); a3 += nwc * bfbits_hi(q.y);
                a4 += nwc * bfbits_lo(q.z); a5 += nwc * bfbits_hi(q.z);
                a6 += nwc * bfbits_lo(q.w); a7 += nwc * bfbits_hi(q.w);
            }
        }
    } else {
        const float* xf = (const float*)X;
        const float* p0 = xf + (size_t)v * 512 + d8;
        float4v f0 = *(const float4v*)p0, f1 = *(const float4v*)(p0 + 4);
        a0 = s2 * f0[0]; a1 = s2 * f0[1]; a2 = s2 * f0[2]; a3 = s2 * f0[3];
        a4 = s2 * f1[0]; a5 = s2 * f1[1]; a6 = s2 * f1[2]; a7 = s2 * f1[3];
        for (int p = rowptr[v]; p < pend; ++p) {
            int u = csr_src[p];
            float nw = dinv[u] * dv;
            const float* pu = xf + (size_t)u * 512 + d8;
            float4v g0 = *(const float4v*)pu, g1 = *(const float4v*)(pu + 4);
            a0 += nw * g0[0]; a1 += nw * g0[1]; a2 += nw * g0[2]; a3 += nw * g0[3];
            a4 += nw * g1[0]; a5 += nw * g1[1]; a6 += nw * g1[2]; a7 += nw * g1[3];
        }
    }
    bf16 o[8];
    o[0] = __float2bfloat16(a0); o[1] = __float2bfloat16(a1);
    o[2] = __float2bfloat16(a2); o[3] = __float2bfloat16(a3);
    o[4] = __float2bfloat16(a4); o[5] = __float2bfloat16(a5);
    o[6] = __float2bfloat16(a6); o[7] = __float2bfloat16(a7);
    *(uint4*)(ax + (size_t)v * 512 + d8) = *(uint4*)o;
}

// ---------------- fused GEMM v2: 64-row tiles for TLP ----------------
// h2 += relu(ax@W1+b1) @ W2, K-sliced over 4 col-chunks with atomics.
// R7 counters: 26.6% occupancy, all pipes idle -> latency wall at ~2 resident
// blocks/CU. Shrink tile 128->64 rows: LDS 32->24 KB, lighter blocks, up to
// 6 blocks/CU (24 waves). Same proven 2-barrier loop. Phase 2 is WAVE-
// PRIVATE (each wave writes+reads only its own 16 R-rows).
__global__ __launch_bounds__(256, 4) void k_fgemm64(
    const bf16* __restrict__ ax, const bf16* __restrict__ W1T,
    const float* __restrict__ b1c, const bf16* __restrict__ W2T,
    float* __restrict__ h2, int rows_per_xcd, int n_row_tiles) {
    const int b = blockIdx.x;
    const int xcd = b & 7;
    const int s = b >> 3;
    const int col_t = s & 3;          // 4 col-chunks of 128 (same-XCD grouping)
    const int lr = s >> 2;
    const int row_t = xcd * rows_per_xcd + lr;
    if (row_t >= n_row_tiles) return;

    __shared__ bf16 smem[12288];      // 24 KiB: As(8K)|Bs(16K) ph1; R(16K) ph2
    bf16* As = smem;                  // [64][64]
    bf16* Bs = smem + 4096;           // [128][64]
    const int tid = threadIdx.x;
    const int wave = tid >> 6, lane = tid & 63;
    const int row0 = row_t * 64;
    const int gc0 = col_t * 128;

    const int rb16 = wave * 16;
    const int frow = lane & 15;
    const int fk = lane >> 4;

    float4v acc[8];
#pragma unroll
    for (int j = 0; j < 8; j++) acc[j] = (float4v){0.f, 0.f, 0.f, 0.f};

    // ---- phase 1: acc = ax_tile(64 rows) @ W1T[gc0..gc0+127] ----
    for (int k0 = 0; k0 < DFEAT; k0 += 64) {
        __syncthreads();
#pragma unroll
        for (int t = 0; t < 2; ++t) {             // A: 64 rows, 2 loads/lane
            int g8 = wave * 2 + t;
            int r = g8 * 8 + (lane >> 3);
            int gr = row0 + r; if (gr >= NNODES) gr = NNODES - 1;
            int ck = (lane & 7) ^ (r & 7);
            load_lds16(ax + (size_t)gr * DFEAT + k0 + ck * 8, &As[g8 * 8 * 64]);
        }
#pragma unroll
        for (int t = 0; t < 4; ++t) {             // B: 128 cols, 4 loads/lane
            int g8 = wave * 4 + t;
            int cl = g8 * 8 + (lane >> 3);
            int ck = (lane & 7) ^ (cl & 7);
            load_lds16(W1T + (size_t)(gc0 + cl) * DFEAT + k0 + ck * 8, &Bs[g8 * 8 * 64]);
        }
        __syncthreads();
#pragma unroll
        for (int ki = 0; ki < 2; ++ki) {
            const int cc = ki * 4 + fk;
            int r = rb16 + frow;
            short8 a = *(const short8*)&As[r * 64 + (cc ^ (r & 7)) * 8];
            short8 b8[8];
#pragma unroll
            for (int j = 0; j < 8; j++) {
                int cl = j * 16 + frow;
                b8[j] = *(const short8*)&Bs[cl * 64 + (cc ^ (cl & 7)) * 8];
            }
#pragma unroll
            for (int j = 0; j < 8; j++)
                acc[j] = __builtin_amdgcn_mfma_f32_16x16x32_bf16(a, b8[j], acc[j], 0, 0, 0);
        }
    }

    // ---- bias + relu -> R [64 rows][128 cols] swizzled into smem ----
    __syncthreads();   // all waves past their last As/Bs reads
    {
        float bias[8];
#pragma unroll
        for (int j = 0; j < 8; j++) bias[j] = b1c[gc0 + j * 16 + frow];
#pragma unroll
        for (int r = 0; r < 4; r++) {
            int row = rb16 + fk * 4 + r;
#pragma unroll
            for (int j = 0; j < 8; j++) {
                int col = j * 16 + frow;
                float v = acc[j][r] + bias[j];
                v = v > 0.f ? v : 0.f;
                int ck2 = (col >> 3) ^ (row & 7);
                smem[row * 128 + ck2 * 8 + (col & 7)] = __float2bfloat16(v);
            }
        }
    }
    __syncthreads();   // (conservative; phase 2 is wave-private)

    // ---- phase 2: acc2 = R(own 16 rows) @ W2T[:, gc0..gc0+127]^T ----
    float4v acc2[4];
#pragma unroll
    for (int j = 0; j < 4; j++) acc2[j] = (float4v){0.f, 0.f, 0.f, 0.f};
#pragma unroll
    for (int ks = 0; ks < 4; ++ks) {
        const int kk = ks * 32 + fk * 8;
        const int p = kk >> 3;
        int row = rb16 + frow;
        short8 a2 = *(const short8*)&smem[row * 128 + ((p ^ (row & 7)) * 8)];
        short8 b2f[4];
#pragma unroll
        for (int j = 0; j < 4; j++) {
            int n = j * 16 + frow;
            b2f[j] = *(const short8*)(W2T + (size_t)n * HID + gc0 + kk);
        }
#pragma unroll
        for (int j = 0; j < 4; j++)
            acc2[j] = __builtin_amdgcn_mfma_f32_16x16x32_bf16(a2, b2f[j], acc2[j], 0, 0, 0);
    }

    // ---- epilogue: atomic accumulate K-slice partial into h2 ----
#pragma unroll
    for (int r = 0; r < 4; r++) {
        int grow = row0 + rb16 + fk * 4 + r;
        if (grow < NNODES) {
#pragma unroll
            for (int j = 0; j < 4; j++)
                atomicAdd(&h2[(size_t)grow * 64 + j * 16 + frow], acc2[j][r]);
        }
    }
}

// ---------------- layer2 aggregation + bias -> out (h2 stride 64) -------------
__global__ __launch_bounds__(256) void k_agg2(const float* __restrict__ h2,
                                              const int* __restrict__ rowptr,
                                              const int* __restrict__ csr_src,
                                              const float* __restrict__ dinv,
                                              const float* __restrict__ b2c,
                                              void* out, const int* flags) {
    int v = blockIdx.x * 4 + (threadIdx.x >> 6);
    int d = threadIdx.x & 63;
    if (v >= NNODES || d >= NCLS) return;
    float dv = dinv[v];
    float acc = dv * dv * h2[(size_t)v * 64 + d];
    int pend = rowptr[v + 1];
    for (int p = rowptr[v]; p < pend; p += 4) {
        int j1 = (p + 1 < pend) ? p + 1 : p;
        int j2 = (p + 2 < pend) ? p + 2 : p;
        int j3 = (p + 3 < pend) ? p + 3 : p;
        int u0 = csr_src[p], u1 = csr_src[j1];
        int u2 = csr_src[j2], u3 = csr_src[j3];
        float nw0 = dinv[u0] * dv;
        float nw1 = (p + 1 < pend) ? dinv[u1] * dv : 0.f;
        float nw2 = (p + 2 < pend) ? dinv[u2] * dv : 0.f;
        float nw3 = (p + 3 < pend) ? dinv[u3] * dv : 0.f;
        float q0 = h2[(size_t)u0 * 64 + d];
        float q1 = h2[(size_t)u1 * 64 + d];
        float q2 = h2[(size_t)u2 * 64 + d];
        float q3 = h2[(size_t)u3 * 64 + d];
        acc += nw0 * q0 + nw1 * q1 + nw2 * q2 + nw3 * q3;
    }
    acc += b2c[d];
    size_t o = (size_t)v * NCLS + d;
    if (flags[0]) ((bf16*)out)[o] = __float2bfloat16(acc);
    else          ((float*)out)[o] = acc;
}

extern "C" void kernel_launch(void* const* d_in, const int* in_sizes, int n_in,
                              void* d_out, int out_size, void* d_ws, size_t ws_size,
                              hipStream_t stream) {
    const void* x  = d_in[0];
    const void* ei = d_in[1];
    const void* W1 = d_in[2];
    const void* b1 = d_in[3];
    const void* W2 = d_in[4];
    const void* b2 = d_in[5];

    char* base = (char*)d_ws;
    auto alloc = [&](size_t bytes) -> char* {
        char* p = base;
        base += (bytes + 255) & ~(size_t)255;
        return p;
    };
    int*   flags  = (int*)alloc(64);
    int*   cnt    = (int*)alloc(sizeof(int) * NNODES);
    int*   part   = (int*)alloc(sizeof(int) * 256);
    int*   rowptr = (int*)alloc(sizeof(int) * (NNODES + 1));
    int*   cursor = (int*)alloc(sizeof(int) * NNODES);
    int*   csr    = (int*)alloc(sizeof(int) * NEDGES);
    float* dinv   = (float*)alloc(sizeof(float) * NNODES);
    bf16*  W1T    = (bf16*)alloc(sizeof(bf16) * DFEAT * HID);
    float* b1c    = (float*)alloc(sizeof(float) * HID);
    bf16*  W2T    = (bf16*)alloc(sizeof(bf16) * 64 * HID);
    float* b2c    = (float*)alloc(sizeof(float) * 64);
    float* h2     = (float*)alloc(sizeof(float) * (size_t)NNODES * 64);
    bf16*  ax     = (bf16*)alloc(sizeof(bf16) * (size_t)NNODES * DFEAT);

    // fused prep: detect + zero(cnt) + zero(h2) + all weight/bias conversions
    k_prep0<<<PR_GRID, 256, 0, stream>>>(x, ei, W1, b1, W2, b2, flags,
                                         (unsigned int*)cnt, W1T, b1c, W2T, b2c, h2);
    k_count<<<(NEDGES + 255) / 256, 256, 0, stream>>>(ei, cnt, flags);
    const int nsb = (NNODES + 255) / 256;  // 196
    k_scan_part_dinv<<<nsb, 256, 0, stream>>>(cnt, part, dinv);
    k_scan_off<<<1, 256, 0, stream>>>(part, nsb);
    k_scan_fin<<<nsb, 256, 0, stream>>>(cnt, part, rowptr, cursor);
    k_fill<<<(NEDGES + 255) / 256, 256, 0, stream>>>(ei, cursor, csr, flags);

    // ax = N·X  (reorder: N(XW1) == (NX)W1)
    k_aggx<<<(NNODES + 3) / 4, 256, 0, stream>>>(x, rowptr, csr, dinv, ax, flags);

    // fused: h2 += relu(ax@W1+b1) @ W2   (3136 blocks: 8 xcd x 98 x 4 chunks)
    const int rowblocks = (NNODES + 63) / 64;        // 782
    const int rows_per_xcd = (rowblocks + 7) / 8;    // 98
    k_fgemm64<<<8 * rows_per_xcd * 4, 256, 0, stream>>>(ax, W1T, b1c, W2T, h2,
                                                        rows_per_xcd, rowblocks);

    k_agg2<<<(NNODES + 3) / 4, 256, 0, stream>>>(h2, rowptr, csr, dinv, b2c, d_out, flags);
}

// Round 9
// 300.659 us; speedup vs baseline: 1.4126x; 1.0506x over previous
//
#include <hip/hip_runtime.h>
#include <hip/hip_bf16.h>

#define NNODES 50000
#define NEDGES 150000
#define DFEAT  512
#define HID    512
#define NCLS   47
#define ELLW   32

typedef __hip_bfloat16 bf16;
typedef __attribute__((ext_vector_type(8))) short short8;
typedef __attribute__((ext_vector_type(4))) float float4v;

typedef const __attribute__((address_space(1))) unsigned int* gas_t;
typedef __attribute__((address_space(3))) unsigned int* las_t;
__device__ __forceinline__ void load_lds16(const void* g, void* l) {
    __builtin_amdgcn_global_load_lds((gas_t)g, (las_t)l, 16, 0, 0);
}

__device__ __forceinline__ float bfbits_lo(unsigned int w) {
    return __uint_as_float((w & 0xFFFFu) << 16);
}
__device__ __forceinline__ float bfbits_hi(unsigned int w) {
    return __uint_as_float(w & 0xFFFF0000u);
}

__device__ __forceinline__ int eidx(const void* ei, int half, int e, int is64) {
    if (is64) return (int)((const long long*)ei)[(size_t)half * NEDGES + e];
    return ((const int*)ei)[half * NEDGES + e];
}

// ---------------- fused prep kernel: role-dispatched by blockIdx ----------------
#define ZB ((NNODES + 255) / 256)
#define NZH2 ((NNODES * 64 / 4 + 255) / 256)   // h2 zero: float4 per thread
#define PR_ZH2 (1 + ZB)
#define PR_W1T (PR_ZH2 + NZH2)
#define PR_B1  (PR_W1T + 1024)
#define PR_W2T (PR_B1 + 2)
#define PR_B2  (PR_W2T + 128)
#define PR_GRID (PR_B2 + 1)

__global__ __launch_bounds__(256) void k_prep0(
    const void* x, const void* ei, const void* W1, const void* b1,
    const void* W2, const void* b2, int* flags, unsigned int* cnt,
    bf16* W1T, float* b1c, bf16* W2T, float* b2c, float* h2) {
    __shared__ int sh[128];
    __shared__ int shflag;
    const int b = blockIdx.x, t = threadIdx.x;

    if (b >= 1 && b < 1 + ZB) {              // zero cnt
        int i = (b - 1) * 256 + t;
        if (i < NNODES) cnt[i] = 0u;
        return;
    }
    if (b >= PR_ZH2 && b < PR_W1T) {         // zero h2 (12.8 MB, float4/thread)
        int i = (b - PR_ZH2) * 256 + t;
        if (i < NNODES * 64 / 4)
            ((float4v*)h2)[i] = (float4v){0.f, 0.f, 0.f, 0.f};
        return;
    }

    // local bf16 detection (needed by all cvt roles; role 0 also writes flags)
    if (t < 64) {
        const unsigned short* xs = (const unsigned short*)x;
        int c = 0;
        for (int i = t; i < 256; i += 64) {
            unsigned int e = (xs[2 * i] >> 7) & 0xFF;
            c += (e >= 117 && e <= 130) ? 1 : 0;
        }
        sh[t] = c;
        if (b == 0) {
            const int* w = (const int*)ei;
            int o = 0;
            for (int i = 2 * t + 1; i < 512; i += 128) o |= w[i];
            sh[64 + t] = o;
        }
    }
    __syncthreads();
    if (t == 0) {
        int C = 0;
        for (int i = 0; i < 64; i++) C += sh[i];
        shflag = (C > 128) ? 1 : 0;
        if (b == 0) {
            int O = 0;
            for (int i = 0; i < 64; i++) O |= sh[64 + i];
            flags[0] = shflag;
            flags[1] = (O == 0) ? 1 : 0;
        }
    }
    __syncthreads();
    const int isb = shflag;

    if (b == 0) return;

    if (b >= PR_W1T && b < PR_B1) {          // W1 [K][N] -> W1T bf16 [N][K]
        int i = (b - PR_W1T) * 256 + t;
        int k = i / HID, n = i % HID;
        float v = isb ? __bfloat162float(((const bf16*)W1)[i]) : ((const float*)W1)[i];
        W1T[(size_t)n * DFEAT + k] = __float2bfloat16(v);
    } else if (b >= PR_B1 && b < PR_W2T) {   // b1 -> f32
        int i = (b - PR_B1) * 256 + t;
        if (i < HID)
            b1c[i] = isb ? __bfloat162float(((const bf16*)b1)[i]) : ((const float*)b1)[i];
    } else if (b >= PR_W2T && b < PR_B2) {   // W2 [K][47] -> W2T bf16 [64][512] pad
        int i = (b - PR_W2T) * 256 + t;
        int n = i / HID, k = i % HID;
        float v = 0.0f;
        if (n < NCLS) {
            size_t idx = (size_t)k * NCLS + n;
            v = isb ? __bfloat162float(((const bf16*)W2)[idx]) : ((const float*)W2)[idx];
        }
        W2T[(size_t)n * HID + k] = __float2bfloat16(v);
    } else if (b == PR_B2) {                 // b2 -> f32
        if (t < NCLS)
            b2c[t] = isb ? __bfloat162float(((const bf16*)b2)[t]) : ((const float*)b2)[t];
    }
}

// ---------------- ELL build: count + fill in ONE kernel ----------------
// slot = atomicAdd(cnt[v]); ell[v*32+slot] = u. Replaces count + 3-kernel
// scan + fill (CSR). 32 slots: P(Pois(3) >= 32) ~ 1e-20; min(deg,32) guard
// in consumers prevents OOB regardless. dinv deleted: consumers compute
// rsqrtf(1+cnt[.]) inline (same 4B load; VALU had 93% headroom).
__global__ void k_fill_ell(const void* ei, int* cnt, int* ell, const int* flags) {
    int e = blockIdx.x * blockDim.x + threadIdx.x;
    if (e >= NEDGES) return;
    int is64 = flags[1];
    int v = eidx(ei, 1, e, is64);
    int u = eidx(ei, 0, e, is64);
    int slot = atomicAdd(&cnt[v], 1);
    if (slot < ELLW) ell[v * ELLW + slot] = u;
}

// ---------------- aggx: ax = D^-1/2 (A+I) D^-1/2 X  (bf16 out) ----------------
// Roofline'd at ~77us (R8: serial/chunk4/chunk8 all identical; 200 MB random
// 1KB-row gather at ~3.3 TB/s combined service rate). ELL + inline rsqrt.
__global__ __launch_bounds__(256) void k_aggx(const void* __restrict__ X,
                                              const int* __restrict__ cnt,
                                              const int* __restrict__ ell,
                                              bf16* __restrict__ ax,
                                              const int* __restrict__ flags) {
    int v = blockIdx.x * 4 + (threadIdx.x >> 6);
    int lane = threadIdx.x & 63;
    if (v >= NNODES) return;
    int d8 = lane * 8;
    int degr = cnt[v];
    int deg = degr < ELLW ? degr : ELLW;
    float dv = rsqrtf(1.0f + (float)degr);
    float s2 = dv * dv;
    const int* er = ell + (size_t)v * ELLW;
    float a0, a1, a2, a3, a4, a5, a6, a7;
    if (flags[0]) {
        const bf16* xb = (const bf16*)X;
        uint4 w = *(const uint4*)(xb + (size_t)v * 512 + d8);
        a0 = s2 * bfbits_lo(w.x); a1 = s2 * bfbits_hi(w.x);
        a2 = s2 * bfbits_lo(w.y); a3 = s2 * bfbits_hi(w.y);
        a4 = s2 * bfbits_lo(w.z); a5 = s2 * bfbits_hi(w.z);
        a6 = s2 * bfbits_lo(w.w); a7 = s2 * bfbits_hi(w.w);
        for (int p = 0; p < deg; p += 8) {
            int u[8]; float nw[8];
#pragma unroll
            for (int c = 0; c < 8; ++c) {
                int jp = (p + c < deg) ? p + c : p;
                u[c] = er[jp];
            }
#pragma unroll
            for (int c = 0; c < 8; ++c)
                nw[c] = (p + c < deg) ? rsqrtf(1.0f + (float)cnt[u[c]]) * dv : 0.f;
#pragma unroll
            for (int c = 0; c < 8; ++c) {
                uint4 q = *(const uint4*)(xb + (size_t)u[c] * 512 + d8);
                float nwc = nw[c];
                a0 += nwc * bfbits_lo(q.x); a1 += nwc * bfbits_hi(q.x);
                a2 += nwc * bfbits_lo(q.y); a3 += nwc * bfbits_hi(q.y);
                a4 += nwc * bfbits_lo(q.z); a5 += nwc * bfbits_hi(q.z);
                a6 += nwc * bfbits_lo(q.w); a7 += nwc * bfbits_hi(q.w);
            }
        }
    } else {
        const float* xf = (const float*)X;
        const float* p0 = xf + (size_t)v * 512 + d8;
        float4v f0 = *(const float4v*)p0, f1 = *(const float4v*)(p0 + 4);
        a0 = s2 * f0[0]; a1 = s2 * f0[1]; a2 = s2 * f0[2]; a3 = s2 * f0[3];
        a4 = s2 * f1[0]; a5 = s2 * f1[1]; a6 = s2 * f1[2]; a7 = s2 * f1[3];
        for (int p = 0; p < deg; ++p) {
            int u = er[p];
            float nw = rsqrtf(1.0f + (float)cnt[u]) * dv;
            const float* pu = xf + (size_t)u * 512 + d8;
            float4v g0 = *(const float4v*)pu, g1 = *(const float4v*)(pu + 4);
            a0 += nw * g0[0]; a1 += nw * g0[1]; a2 += nw * g0[2]; a3 += nw * g0[3];
            a4 += nw * g1[0]; a5 += nw * g1[1]; a6 += nw * g1[2]; a7 += nw * g1[3];
        }
    }
    bf16 o[8];
    o[0] = __float2bfloat16(a0); o[1] = __float2bfloat16(a1);
    o[2] = __float2bfloat16(a2); o[3] = __float2bfloat16(a3);
    o[4] = __float2bfloat16(a4); o[5] = __float2bfloat16(a5);
    o[6] = __float2bfloat16(a6); o[7] = __float2bfloat16(a7);
    *(uint4*)(ax + (size_t)v * 512 + d8) = *(uint4*)o;
}

// ---------------- fused GEMM v2: 64-row tiles (unchanged from R8) ----------------
__global__ __launch_bounds__(256, 4) void k_fgemm64(
    const bf16* __restrict__ ax, const bf16* __restrict__ W1T,
    const float* __restrict__ b1c, const bf16* __restrict__ W2T,
    float* __restrict__ h2, int rows_per_xcd, int n_row_tiles) {
    const int b = blockIdx.x;
    const int xcd = b & 7;
    const int s = b >> 3;
    const int col_t = s & 3;          // 4 col-chunks of 128 (same-XCD grouping)
    const int lr = s >> 2;
    const int row_t = xcd * rows_per_xcd + lr;
    if (row_t >= n_row_tiles) return;

    __shared__ bf16 smem[12288];      // 24 KiB: As(8K)|Bs(16K) ph1; R(16K) ph2
    bf16* As = smem;                  // [64][64]
    bf16* Bs = smem + 4096;           // [128][64]
    const int tid = threadIdx.x;
    const int wave = tid >> 6, lane = tid & 63;
    const int row0 = row_t * 64;
    const int gc0 = col_t * 128;

    const int rb16 = wave * 16;
    const int frow = lane & 15;
    const int fk = lane >> 4;

    float4v acc[8];
#pragma unroll
    for (int j = 0; j < 8; j++) acc[j] = (float4v){0.f, 0.f, 0.f, 0.f};

    // ---- phase 1: acc = ax_tile(64 rows) @ W1T[gc0..gc0+127] ----
    for (int k0 = 0; k0 < DFEAT; k0 += 64) {
        __syncthreads();
#pragma unroll
        for (int t = 0; t < 2; ++t) {             // A: 64 rows, 2 loads/lane
            int g8 = wave * 2 + t;
            int r = g8 * 8 + (lane >> 3);
            int gr = row0 + r; if (gr >= NNODES) gr = NNODES - 1;
            int ck = (lane & 7) ^ (r & 7);
            load_lds16(ax + (size_t)gr * DFEAT + k0 + ck * 8, &As[g8 * 8 * 64]);
        }
#pragma unroll
        for (int t = 0; t < 4; ++t) {             // B: 128 cols, 4 loads/lane
            int g8 = wave * 4 + t;
            int cl = g8 * 8 + (lane >> 3);
            int ck = (lane & 7) ^ (cl & 7);
            load_lds16(W1T + (size_t)(gc0 + cl) * DFEAT + k0 + ck * 8, &Bs[g8 * 8 * 64]);
        }
        __syncthreads();
#pragma unroll
        for (int ki = 0; ki < 2; ++ki) {
            const int cc = ki * 4 + fk;
            int r = rb16 + frow;
            short8 a = *(const short8*)&As[r * 64 + (cc ^ (r & 7)) * 8];
            short8 b8[8];
#pragma unroll
            for (int j = 0; j < 8; j++) {
                int cl = j * 16 + frow;
                b8[j] = *(const short8*)&Bs[cl * 64 + (cc ^ (cl & 7)) * 8];
            }
#pragma unroll
            for (int j = 0; j < 8; j++)
                acc[j] = __builtin_amdgcn_mfma_f32_16x16x32_bf16(a, b8[j], acc[j], 0, 0, 0);
        }
    }

    // ---- bias + relu -> R [64 rows][128 cols] swizzled into smem ----
    __syncthreads();   // all waves past their last As/Bs reads
    {
        float bias[8];
#pragma unroll
        for (int j = 0; j < 8; j++) bias[j] = b1c[gc0 + j * 16 + frow];
#pragma unroll
        for (int r = 0; r < 4; r++) {
            int row = rb16 + fk * 4 + r;
#pragma unroll
            for (int j = 0; j < 8; j++) {
                int col = j * 16 + frow;
                float v = acc[j][r] + bias[j];
                v = v > 0.f ? v : 0.f;
                int ck2 = (col >> 3) ^ (row & 7);
                smem[row * 128 + ck2 * 8 + (col & 7)] = __float2bfloat16(v);
            }
        }
    }
    __syncthreads();   // (conservative; phase 2 is wave-private)

    // ---- phase 2: acc2 = R(own 16 rows) @ W2T[:, gc0..gc0+127]^T ----
    float4v acc2[4];
#pragma unroll
    for (int j = 0; j < 4; j++) acc2[j] = (float4v){0.f, 0.f, 0.f, 0.f};
#pragma unroll
    for (int ks = 0; ks < 4; ++ks) {
        const int kk = ks * 32 + fk * 8;
        const int p = kk >> 3;
        int row = rb16 + frow;
        short8 a2 = *(const short8*)&smem[row * 128 + ((p ^ (row & 7)) * 8)];
        short8 b2f[4];
#pragma unroll
        for (int j = 0; j < 4; j++) {
            int n = j * 16 + frow;
            b2f[j] = *(const short8*)(W2T + (size_t)n * HID + gc0 + kk);
        }
#pragma unroll
        for (int j = 0; j < 4; j++)
            acc2[j] = __builtin_amdgcn_mfma_f32_16x16x32_bf16(a2, b2f[j], acc2[j], 0, 0, 0);
    }

    // ---- epilogue: atomic accumulate K-slice partial into h2 ----
#pragma unroll
    for (int r = 0; r < 4; r++) {
        int grow = row0 + rb16 + fk * 4 + r;
        if (grow < NNODES) {
#pragma unroll
            for (int j = 0; j < 4; j++)
                atomicAdd(&h2[(size_t)grow * 64 + j * 16 + frow], acc2[j][r]);
        }
    }
}

// ---------------- layer2 aggregation + bias -> out (h2 stride 64) -------------
__global__ __launch_bounds__(256) void k_agg2(const float* __restrict__ h2,
                                              const int* __restrict__ cnt,
                                              const int* __restrict__ ell,
                                              const float* __restrict__ b2c,
                                              void* out, const int* flags) {
    int v = blockIdx.x * 4 + (threadIdx.x >> 6);
    int d = threadIdx.x & 63;
    if (v >= NNODES || d >= NCLS) return;
    int degr = cnt[v];
    int deg = degr < ELLW ? degr : ELLW;
    float dv = rsqrtf(1.0f + (float)degr);
    const int* er = ell + (size_t)v * ELLW;
    float acc = dv * dv * h2[(size_t)v * 64 + d];
    for (int p = 0; p < deg; p += 4) {
        int u0 = er[(p < deg) ? p : p];
        int u1 = er[(p + 1 < deg) ? p + 1 : p];
        int u2 = er[(p + 2 < deg) ? p + 2 : p];
        int u3 = er[(p + 3 < deg) ? p + 3 : p];
        float nw0 = rsqrtf(1.0f + (float)cnt[u0]) * dv;
        float nw1 = (p + 1 < deg) ? rsqrtf(1.0f + (float)cnt[u1]) * dv : 0.f;
        float nw2 = (p + 2 < deg) ? rsqrtf(1.0f + (float)cnt[u2]) * dv : 0.f;
        float nw3 = (p + 3 < deg) ? rsqrtf(1.0f + (float)cnt[u3]) * dv : 0.f;
        float q0 = h2[(size_t)u0 * 64 + d];
        float q1 = h2[(size_t)u1 * 64 + d];
        float q2 = h2[(size_t)u2 * 64 + d];
        float q3 = h2[(size_t)u3 * 64 + d];
        acc += nw0 * q0 + nw1 * q1 + nw2 * q2 + nw3 * q3;
    }
    acc += b2c[d];
    size_t o = (size_t)v * NCLS + d;
    if (flags[0]) ((bf16*)out)[o] = __float2bfloat16(acc);
    else          ((float*)out)[o] = acc;
}

extern "C" void kernel_launch(void* const* d_in, const int* in_sizes, int n_in,
                              void* d_out, int out_size, void* d_ws, size_t ws_size,
                              hipStream_t stream) {
    const void* x  = d_in[0];
    const void* ei = d_in[1];
    const void* W1 = d_in[2];
    const void* b1 = d_in[3];
    const void* W2 = d_in[4];
    const void* b2 = d_in[5];

    char* base = (char*)d_ws;
    auto alloc = [&](size_t bytes) -> char* {
        char* p = base;
        base += (bytes + 255) & ~(size_t)255;
        return p;
    };
    int*   flags  = (int*)alloc(64);
    int*   cnt    = (int*)alloc(sizeof(int) * NNODES);
    int*   ell    = (int*)alloc(sizeof(int) * (size_t)NNODES * ELLW);
    bf16*  W1T    = (bf16*)alloc(sizeof(bf16) * DFEAT * HID);
    float* b1c    = (float*)alloc(sizeof(float) * HID);
    bf16*  W2T    = (bf16*)alloc(sizeof(bf16) * 64 * HID);
    float* b2c    = (float*)alloc(sizeof(float) * 64);
    float* h2     = (float*)alloc(sizeof(float) * (size_t)NNODES * 64);
    bf16*  ax     = (bf16*)alloc(sizeof(bf16) * (size_t)NNODES * DFEAT);

    // 1) fused prep: detect + zero(cnt) + zero(h2) + all weight/bias conversions
    k_prep0<<<PR_GRID, 256, 0, stream>>>(x, ei, W1, b1, W2, b2, flags,
                                         (unsigned int*)cnt, W1T, b1c, W2T, b2c, h2);
    // 2) ELL build (count + fill in one kernel; no scans, no dinv)
    k_fill_ell<<<(NEDGES + 255) / 256, 256, 0, stream>>>(ei, cnt, ell, flags);
    // 3) ax = N·X  (reorder: N(XW1) == (NX)W1)
    k_aggx<<<(NNODES + 3) / 4, 256, 0, stream>>>(x, cnt, ell, ax, flags);
    // 4) fused: h2 += relu(ax@W1+b1) @ W2
    const int rowblocks = (NNODES + 63) / 64;        // 782
    const int rows_per_xcd = (rowblocks + 7) / 8;    // 98
    k_fgemm64<<<8 * rows_per_xcd * 4, 256, 0, stream>>>(ax, W1T, b1c, W2T, h2,
                                                        rows_per_xcd, rowblocks);
    // 5) out = N·h2 + b2
    k_agg2<<<(NNODES + 3) / 4, 256, 0, stream>>>(h2, cnt, ell, b2c, d_out, flags);
}

// Round 10
// 296.918 us; speedup vs baseline: 1.4304x; 1.0126x over previous
//
#include <hip/hip_runtime.h>
#include <hip/hip_bf16.h>

#define NNODES 50000
#define NEDGES 150000
#define DFEAT  512
#define HID    512
#define NCLS   47
#define ELLW   32

typedef __hip_bfloat16 bf16;
typedef __attribute__((ext_vector_type(8))) short short8;
typedef __attribute__((ext_vector_type(4))) float float4v;

typedef const __attribute__((address_space(1))) unsigned int* gas_t;
typedef __attribute__((address_space(3))) unsigned int* las_t;
__device__ __forceinline__ void load_lds16(const void* g, void* l) {
    __builtin_amdgcn_global_load_lds((gas_t)g, (las_t)l, 16, 0, 0);
}

__device__ __forceinline__ float bfbits_lo(unsigned int w) {
    return __uint_as_float((w & 0xFFFFu) << 16);
}
__device__ __forceinline__ float bfbits_hi(unsigned int w) {
    return __uint_as_float(w & 0xFFFF0000u);
}

__device__ __forceinline__ int eidx(const void* ei, int half, int e, int is64) {
    if (is64) return (int)((const long long*)ei)[(size_t)half * NEDGES + e];
    return ((const int*)ei)[half * NEDGES + e];
}

// ---------------- fused prep kernel: role-dispatched by blockIdx ----------------
#define ZB ((NNODES + 255) / 256)
#define NZH2 ((NNODES * 64 / 4 + 255) / 256)   // h2 zero: float4 per thread
#define PR_ZH2 (1 + ZB)
#define PR_W1T (PR_ZH2 + NZH2)
#define PR_B1  (PR_W1T + 1024)
#define PR_W2T (PR_B1 + 2)
#define PR_B2  (PR_W2T + 128)
#define PR_GRID (PR_B2 + 1)

__global__ __launch_bounds__(256) void k_prep0(
    const void* x, const void* ei, const void* W1, const void* b1,
    const void* W2, const void* b2, int* flags, unsigned int* cnt,
    bf16* W1T, float* b1c, bf16* W2T, float* b2c, float* h2) {
    __shared__ int sh[128];
    __shared__ int shflag;
    const int b = blockIdx.x, t = threadIdx.x;

    if (b >= 1 && b < 1 + ZB) {              // zero cnt
        int i = (b - 1) * 256 + t;
        if (i < NNODES) cnt[i] = 0u;
        return;
    }
    if (b >= PR_ZH2 && b < PR_W1T) {         // zero h2 (12.8 MB, float4/thread)
        int i = (b - PR_ZH2) * 256 + t;
        if (i < NNODES * 64 / 4)
            ((float4v*)h2)[i] = (float4v){0.f, 0.f, 0.f, 0.f};
        return;
    }

    // local bf16 detection (needed by all cvt roles; role 0 also writes flags)
    if (t < 64) {
        const unsigned short* xs = (const unsigned short*)x;
        int c = 0;
        for (int i = t; i < 256; i += 64) {
            unsigned int e = (xs[2 * i] >> 7) & 0xFF;
            c += (e >= 117 && e <= 130) ? 1 : 0;
        }
        sh[t] = c;
        if (b == 0) {
            const int* w = (const int*)ei;
            int o = 0;
            for (int i = 2 * t + 1; i < 512; i += 128) o |= w[i];
            sh[64 + t] = o;
        }
    }
    __syncthreads();
    if (t == 0) {
        int C = 0;
        for (int i = 0; i < 64; i++) C += sh[i];
        shflag = (C > 128) ? 1 : 0;
        if (b == 0) {
            int O = 0;
            for (int i = 0; i < 64; i++) O |= sh[64 + i];
            flags[0] = shflag;
            flags[1] = (O == 0) ? 1 : 0;
        }
    }
    __syncthreads();
    const int isb = shflag;

    if (b == 0) return;

    if (b >= PR_W1T && b < PR_B1) {          // W1 [K][N] -> W1T bf16 [N][K]
        int i = (b - PR_W1T) * 256 + t;
        int k = i / HID, n = i % HID;
        float v = isb ? __bfloat162float(((const bf16*)W1)[i]) : ((const float*)W1)[i];
        W1T[(size_t)n * DFEAT + k] = __float2bfloat16(v);
    } else if (b >= PR_B1 && b < PR_W2T) {   // b1 -> f32
        int i = (b - PR_B1) * 256 + t;
        if (i < HID)
            b1c[i] = isb ? __bfloat162float(((const bf16*)b1)[i]) : ((const float*)b1)[i];
    } else if (b >= PR_W2T && b < PR_B2) {   // W2 [K][47] -> W2T bf16 [64][512] pad
        int i = (b - PR_W2T) * 256 + t;
        int n = i / HID, k = i % HID;
        float v = 0.0f;
        if (n < NCLS) {
            size_t idx = (size_t)k * NCLS + n;
            v = isb ? __bfloat162float(((const bf16*)W2)[idx]) : ((const float*)W2)[idx];
        }
        W2T[(size_t)n * HID + k] = __float2bfloat16(v);
    } else if (b == PR_B2) {                 // b2 -> f32, zero-padded to 64
        if (t < 64)
            b2c[t] = (t < NCLS)
                ? (isb ? __bfloat162float(((const bf16*)b2)[t]) : ((const float*)b2)[t])
                : 0.0f;
    }
}

// ---------------- ELL build: count + fill in ONE kernel ----------------
__global__ void k_fill_ell(const void* ei, int* cnt, int* ell, const int* flags) {
    int e = blockIdx.x * blockDim.x + threadIdx.x;
    if (e >= NEDGES) return;
    int is64 = flags[1];
    int v = eidx(ei, 1, e, is64);
    int u = eidx(ei, 0, e, is64);
    int slot = atomicAdd(&cnt[v], 1);
    if (slot < ELLW) ell[v * ELLW + slot] = u;
}

// ---------------- aggx: ax = D^-1/2 (A+I) D^-1/2 X  (bf16 out) ----------------
// Roofline'd at ~77us (R8: serial/chunk4/chunk8 identical; 200 MB random
// 1KB-row gather service ceiling). Frozen.
__global__ __launch_bounds__(256) void k_aggx(const void* __restrict__ X,
                                              const int* __restrict__ cnt,
                                              const int* __restrict__ ell,
                                              bf16* __restrict__ ax,
                                              const int* __restrict__ flags) {
    int v = blockIdx.x * 4 + (threadIdx.x >> 6);
    int lane = threadIdx.x & 63;
    if (v >= NNODES) return;
    int d8 = lane * 8;
    int degr = cnt[v];
    int deg = degr < ELLW ? degr : ELLW;
    float dv = rsqrtf(1.0f + (float)degr);
    float s2 = dv * dv;
    const int* er = ell + (size_t)v * ELLW;
    float a0, a1, a2, a3, a4, a5, a6, a7;
    if (flags[0]) {
        const bf16* xb = (const bf16*)X;
        uint4 w = *(const uint4*)(xb + (size_t)v * 512 + d8);
        a0 = s2 * bfbits_lo(w.x); a1 = s2 * bfbits_hi(w.x);
        a2 = s2 * bfbits_lo(w.y); a3 = s2 * bfbits_hi(w.y);
        a4 = s2 * bfbits_lo(w.z); a5 = s2 * bfbits_hi(w.z);
        a6 = s2 * bfbits_lo(w.w); a7 = s2 * bfbits_hi(w.w);
        for (int p = 0; p < deg; p += 8) {
            int u[8]; float nw[8];
#pragma unroll
            for (int c = 0; c < 8; ++c) {
                int jp = (p + c < deg) ? p + c : p;
                u[c] = er[jp];
            }
#pragma unroll
            for (int c = 0; c < 8; ++c)
                nw[c] = (p + c < deg) ? rsqrtf(1.0f + (float)cnt[u[c]]) * dv : 0.f;
#pragma unroll
            for (int c = 0; c < 8; ++c) {
                uint4 q = *(const uint4*)(xb + (size_t)u[c] * 512 + d8);
                float nwc = nw[c];
                a0 += nwc * bfbits_lo(q.x); a1 += nwc * bfbits_hi(q.x);
                a2 += nwc * bfbits_lo(q.y); a3 += nwc * bfbits_hi(q.y);
                a4 += nwc * bfbits_lo(q.z); a5 += nwc * bfbits_hi(q.z);
                a6 += nwc * bfbits_lo(q.w); a7 += nwc * bfbits_hi(q.w);
            }
        }
    } else {
        const float* xf = (const float*)X;
        const float* p0 = xf + (size_t)v * 512 + d8;
        float4v f0 = *(const float4v*)p0, f1 = *(const float4v*)(p0 + 4);
        a0 = s2 * f0[0]; a1 = s2 * f0[1]; a2 = s2 * f0[2]; a3 = s2 * f0[3];
        a4 = s2 * f1[0]; a5 = s2 * f1[1]; a6 = s2 * f1[2]; a7 = s2 * f1[3];
        for (int p = 0; p < deg; ++p) {
            int u = er[p];
            float nw = rsqrtf(1.0f + (float)cnt[u]) * dv;
            const float* pu = xf + (size_t)u * 512 + d8;
            float4v g0 = *(const float4v*)pu, g1 = *(const float4v*)(pu + 4);
            a0 += nw * g0[0]; a1 += nw * g0[1]; a2 += nw * g0[2]; a3 += nw * g0[3];
            a4 += nw * g1[0]; a5 += nw * g1[1]; a6 += nw * g1[2]; a7 += nw * g1[3];
        }
    }
    bf16 o[8];
    o[0] = __float2bfloat16(a0); o[1] = __float2bfloat16(a1);
    o[2] = __float2bfloat16(a2); o[3] = __float2bfloat16(a3);
    o[4] = __float2bfloat16(a4); o[5] = __float2bfloat16(a5);
    o[6] = __float2bfloat16(a6); o[7] = __float2bfloat16(a7);
    *(uint4*)(ax + (size_t)v * 512 + d8) = *(uint4*)o;
}

// ---------------- fused GEMM v2: 64-row tiles (frozen from R8/R9) ----------------
__global__ __launch_bounds__(256, 4) void k_fgemm64(
    const bf16* __restrict__ ax, const bf16* __restrict__ W1T,
    const float* __restrict__ b1c, const bf16* __restrict__ W2T,
    float* __restrict__ h2, int rows_per_xcd, int n_row_tiles) {
    const int b = blockIdx.x;
    const int xcd = b & 7;
    const int s = b >> 3;
    const int col_t = s & 3;          // 4 col-chunks of 128 (same-XCD grouping)
    const int lr = s >> 2;
    const int row_t = xcd * rows_per_xcd + lr;
    if (row_t >= n_row_tiles) return;

    __shared__ bf16 smem[12288];      // 24 KiB: As(8K)|Bs(16K) ph1; R(16K) ph2
    bf16* As = smem;                  // [64][64]
    bf16* Bs = smem + 4096;           // [128][64]
    const int tid = threadIdx.x;
    const int wave = tid >> 6, lane = tid & 63;
    const int row0 = row_t * 64;
    const int gc0 = col_t * 128;

    const int rb16 = wave * 16;
    const int frow = lane & 15;
    const int fk = lane >> 4;

    float4v acc[8];
#pragma unroll
    for (int j = 0; j < 8; j++) acc[j] = (float4v){0.f, 0.f, 0.f, 0.f};

    // ---- phase 1: acc = ax_tile(64 rows) @ W1T[gc0..gc0+127] ----
    for (int k0 = 0; k0 < DFEAT; k0 += 64) {
        __syncthreads();
#pragma unroll
        for (int t = 0; t < 2; ++t) {             // A: 64 rows, 2 loads/lane
            int g8 = wave * 2 + t;
            int r = g8 * 8 + (lane >> 3);
            int gr = row0 + r; if (gr >= NNODES) gr = NNODES - 1;
            int ck = (lane & 7) ^ (r & 7);
            load_lds16(ax + (size_t)gr * DFEAT + k0 + ck * 8, &As[g8 * 8 * 64]);
        }
#pragma unroll
        for (int t = 0; t < 4; ++t) {             // B: 128 cols, 4 loads/lane
            int g8 = wave * 4 + t;
            int cl = g8 * 8 + (lane >> 3);
            int ck = (lane & 7) ^ (cl & 7);
            load_lds16(W1T + (size_t)(gc0 + cl) * DFEAT + k0 + ck * 8, &Bs[g8 * 8 * 64]);
        }
        __syncthreads();
#pragma unroll
        for (int ki = 0; ki < 2; ++ki) {
            const int cc = ki * 4 + fk;
            int r = rb16 + frow;
            short8 a = *(const short8*)&As[r * 64 + (cc ^ (r & 7)) * 8];
            short8 b8[8];
#pragma unroll
            for (int j = 0; j < 8; j++) {
                int cl = j * 16 + frow;
                b8[j] = *(const short8*)&Bs[cl * 64 + (cc ^ (cl & 7)) * 8];
            }
#pragma unroll
            for (int j = 0; j < 8; j++)
                acc[j] = __builtin_amdgcn_mfma_f32_16x16x32_bf16(a, b8[j], acc[j], 0, 0, 0);
        }
    }

    // ---- bias + relu -> R [64 rows][128 cols] swizzled into smem ----
    __syncthreads();   // all waves past their last As/Bs reads
    {
        float bias[8];
#pragma unroll
        for (int j = 0; j < 8; j++) bias[j] = b1c[gc0 + j * 16 + frow];
#pragma unroll
        for (int r = 0; r < 4; r++) {
            int row = rb16 + fk * 4 + r;
#pragma unroll
            for (int j = 0; j < 8; j++) {
                int col = j * 16 + frow;
                float v = acc[j][r] + bias[j];
                v = v > 0.f ? v : 0.f;
                int ck2 = (col >> 3) ^ (row & 7);
                smem[row * 128 + ck2 * 8 + (col & 7)] = __float2bfloat16(v);
            }
        }
    }
    __syncthreads();   // (conservative; phase 2 is wave-private)

    // ---- phase 2: acc2 = R(own 16 rows) @ W2T[:, gc0..gc0+127]^T ----
    float4v acc2[4];
#pragma unroll
    for (int j = 0; j < 4; j++) acc2[j] = (float4v){0.f, 0.f, 0.f, 0.f};
#pragma unroll
    for (int ks = 0; ks < 4; ++ks) {
        const int kk = ks * 32 + fk * 8;
        const int p = kk >> 3;
        int row = rb16 + frow;
        short8 a2 = *(const short8*)&smem[row * 128 + ((p ^ (row & 7)) * 8)];
        short8 b2f[4];
#pragma unroll
        for (int j = 0; j < 4; j++) {
            int n = j * 16 + frow;
            b2f[j] = *(const short8*)(W2T + (size_t)n * HID + gc0 + kk);
        }
#pragma unroll
        for (int j = 0; j < 4; j++)
            acc2[j] = __builtin_amdgcn_mfma_f32_16x16x32_bf16(a2, b2f[j], acc2[j], 0, 0, 0);
    }

    // ---- epilogue: atomic accumulate K-slice partial into h2 ----
#pragma unroll
    for (int r = 0; r < 4; r++) {
        int grow = row0 + rb16 + fk * 4 + r;
        if (grow < NNODES) {
#pragma unroll
            for (int j = 0; j < 4; j++)
                atomicAdd(&h2[(size_t)grow * 64 + j * 16 + frow], acc2[j][r]);
        }
    }
}

// ---------------- layer2 aggregation v2: 4 nodes/wave, float4 lanes ----------
// R9 theory: agg2's cost is per-edge serialized load CHAINS, not bytes (same
// wave-wide instruction count per edge as aggx despite 5x less data). Fix:
// 16-lane groups, one node each -> 4 independent chains/wave x chunk-4 =
// ~16 outstanding gathers (was 4); lane reads float4 (full 64-col h2 row per
// instruction); 60/64 lanes useful (was 47/64).
__global__ __launch_bounds__(256) void k_agg2(const float* __restrict__ h2,
                                              const int* __restrict__ cnt,
                                              const int* __restrict__ ell,
                                              const float* __restrict__ b2c,
                                              void* out, const int* flags) {
    int v = blockIdx.x * 16 + (threadIdx.x >> 4);
    int l = threadIdx.x & 15;
    if (v >= NNODES) return;
    int d4 = l * 4;
    int degr = cnt[v];
    int deg = degr < ELLW ? degr : ELLW;
    float dv = rsqrtf(1.0f + (float)degr);
    const int* er = ell + (size_t)v * ELLW;
    float4v w = *(const float4v*)(h2 + (size_t)v * 64 + d4);
    float s2 = dv * dv;
    float a0 = s2 * w[0], a1 = s2 * w[1], a2 = s2 * w[2], a3 = s2 * w[3];
    for (int p = 0; p < deg; p += 4) {
        int u0 = er[p];
        int u1 = er[(p + 1 < deg) ? p + 1 : p];
        int u2 = er[(p + 2 < deg) ? p + 2 : p];
        int u3 = er[(p + 3 < deg) ? p + 3 : p];
        float nw0 = rsqrtf(1.0f + (float)cnt[u0]) * dv;
        float nw1 = (p + 1 < deg) ? rsqrtf(1.0f + (float)cnt[u1]) * dv : 0.f;
        float nw2 = (p + 2 < deg) ? rsqrtf(1.0f + (float)cnt[u2]) * dv : 0.f;
        float nw3 = (p + 3 < deg) ? rsqrtf(1.0f + (float)cnt[u3]) * dv : 0.f;
        float4v q0 = *(const float4v*)(h2 + (size_t)u0 * 64 + d4);
        float4v q1 = *(const float4v*)(h2 + (size_t)u1 * 64 + d4);
        float4v q2 = *(const float4v*)(h2 + (size_t)u2 * 64 + d4);
        float4v q3 = *(const float4v*)(h2 + (size_t)u3 * 64 + d4);
        a0 += nw0 * q0[0] + nw1 * q1[0] + nw2 * q2[0] + nw3 * q3[0];
        a1 += nw0 * q0[1] + nw1 * q1[1] + nw2 * q2[1] + nw3 * q3[1];
        a2 += nw0 * q0[2] + nw1 * q1[2] + nw2 * q2[2] + nw3 * q3[2];
        a3 += nw0 * q0[3] + nw1 * q1[3] + nw2 * q2[3] + nw3 * q3[3];
    }
    a0 += b2c[d4 + 0]; a1 += b2c[d4 + 1]; a2 += b2c[d4 + 2]; a3 += b2c[d4 + 3];
    size_t base = (size_t)v * NCLS;
    if (flags[0]) {
        bf16* ob = (bf16*)out;
        if (d4 + 0 < NCLS) ob[base + d4 + 0] = __float2bfloat16(a0);
        if (d4 + 1 < NCLS) ob[base + d4 + 1] = __float2bfloat16(a1);
        if (d4 + 2 < NCLS) ob[base + d4 + 2] = __float2bfloat16(a2);
        if (d4 + 3 < NCLS) ob[base + d4 + 3] = __float2bfloat16(a3);
    } else {
        float* of = (float*)out;
        if (d4 + 0 < NCLS) of[base + d4 + 0] = a0;
        if (d4 + 1 < NCLS) of[base + d4 + 1] = a1;
        if (d4 + 2 < NCLS) of[base + d4 + 2] = a2;
        if (d4 + 3 < NCLS) of[base + d4 + 3] = a3;
    }
}

extern "C" void kernel_launch(void* const* d_in, const int* in_sizes, int n_in,
                              void* d_out, int out_size, void* d_ws, size_t ws_size,
                              hipStream_t stream) {
    const void* x  = d_in[0];
    const void* ei = d_in[1];
    const void* W1 = d_in[2];
    const void* b1 = d_in[3];
    const void* W2 = d_in[4];
    const void* b2 = d_in[5];

    char* base = (char*)d_ws;
    auto alloc = [&](size_t bytes) -> char* {
        char* p = base;
        base += (bytes + 255) & ~(size_t)255;
        return p;
    };
    int*   flags  = (int*)alloc(64);
    int*   cnt    = (int*)alloc(sizeof(int) * NNODES);
    int*   ell    = (int*)alloc(sizeof(int) * (size_t)NNODES * ELLW);
    bf16*  W1T    = (bf16*)alloc(sizeof(bf16) * DFEAT * HID);
    float* b1c    = (float*)alloc(sizeof(float) * HID);
    bf16*  W2T    = (bf16*)alloc(sizeof(bf16) * 64 * HID);
    float* b2c    = (float*)alloc(sizeof(float) * 64);
    float* h2     = (float*)alloc(sizeof(float) * (size_t)NNODES * 64);
    bf16*  ax     = (bf16*)alloc(sizeof(bf16) * (size_t)NNODES * DFEAT);

    // 1) fused prep: detect + zero(cnt) + zero(h2) + all weight/bias conversions
    k_prep0<<<PR_GRID, 256, 0, stream>>>(x, ei, W1, b1, W2, b2, flags,
                                         (unsigned int*)cnt, W1T, b1c, W2T, b2c, h2);
    // 2) ELL build (count + fill in one kernel; no scans, no dinv)
    k_fill_ell<<<(NEDGES + 255) / 256, 256, 0, stream>>>(ei, cnt, ell, flags);
    // 3) ax = N·X  (reorder: N(XW1) == (NX)W1)
    k_aggx<<<(NNODES + 3) / 4, 256, 0, stream>>>(x, cnt, ell, ax, flags);
    // 4) fused: h2 += relu(ax@W1+b1) @ W2
    const int rowblocks = (NNODES + 63) / 64;        // 782
    const int rows_per_xcd = (rowblocks + 7) / 8;    // 98
    k_fgemm64<<<8 * rows_per_xcd * 4, 256, 0, stream>>>(ax, W1T, b1c, W2T, h2,
                                                        rows_per_xcd, rowblocks);
    // 5) out = N·h2 + b2  (3125 blocks, 16 nodes/block)
    k_agg2<<<(NNODES + 15) / 16, 256, 0, stream>>>(h2, cnt, ell, b2c, d_out, flags);
}